// Round 1
// baseline (10979.169 us; speedup 1.0000x reference)
//
#include <hip/hip_runtime.h>

// Problem constants (fixed by the reference)
#define T_    2048
#define N_    1024
#define MC_   512
#define KF_   20
#define M_    5
#define J_    (KF_ * MC_)      // 10240 flattened (i,c)
#define NSEG  8
#define SEGLEN (T_ / NSEG)     // 256
#define NIT   14               // Neumann iterations (convergence margin; trim later)

// ---------------------------------------------------------------------------
// Generic fp32 tiled GEMM: C[m,n] = alpha * sum_k A[m,k] * B'[k,n]  (+ Add[m,n])
//   TB=1: B' = B[n,k]  (B row-major N x K, dot-of-rows)
//   TB=0: B' = B[k,n]  (B row-major K x N)
//   Aoff: optional per-segment column-offset rows (O[seg][k]) added to A while
//         staging — used to turn segment-local prefix sums into global ones.
// Tiles: 64x64 output, BK=32, 256 threads, 4x4 micro-tile per thread.
// Requires M%64==0, N%64==0, K%32==0 (all shapes here satisfy this).
// ---------------------------------------------------------------------------
template <int TB>
__global__ __launch_bounds__(256) void gemm_f32(
    const float* __restrict__ A, const float* __restrict__ B,
    const float* __restrict__ Add, const float* __restrict__ Aoff,
    float* __restrict__ C, int Mdim, int Ndim, int Kdim, float alpha)
{
    __shared__ __align__(16) float As[32][68];  // [k][m], padded (68*4B = 16-aligned rows)
    __shared__ __align__(16) float Bs[32][68];  // [k][n]
    const int tid = threadIdx.x;
    const int n0 = blockIdx.x * 64;
    const int m0 = blockIdx.y * 64;
    const int tx = tid & 15, ty = tid >> 4;
    const float* orow = Aoff ? (Aoff + (size_t)(m0 / SEGLEN) * Kdim) : nullptr;
    float acc[4][4] = {};

    for (int kk = 0; kk < Kdim; kk += 32) {
        // Stage A tile (64 rows x 32 k), transposed into As[k][m]
        #pragma unroll
        for (int l = 0; l < 2; ++l) {
            int q = tid * 2 + l;
            int row = q >> 3, kq = q & 7;
            float4 v = *(const float4*)(A + (size_t)(m0 + row) * Kdim + kk + kq * 4);
            if (orow) {
                v.x += orow[kk + kq * 4 + 0];
                v.y += orow[kk + kq * 4 + 1];
                v.z += orow[kk + kq * 4 + 2];
                v.w += orow[kk + kq * 4 + 3];
            }
            As[kq * 4 + 0][row] = v.x;
            As[kq * 4 + 1][row] = v.y;
            As[kq * 4 + 2][row] = v.z;
            As[kq * 4 + 3][row] = v.w;
        }
        if (TB == 1) {
            #pragma unroll
            for (int l = 0; l < 2; ++l) {
                int q = tid * 2 + l;
                int row = q >> 3, kq = q & 7;
                float4 v = *(const float4*)(B + (size_t)(n0 + row) * Kdim + kk + kq * 4);
                Bs[kq * 4 + 0][row] = v.x;
                Bs[kq * 4 + 1][row] = v.y;
                Bs[kq * 4 + 2][row] = v.z;
                Bs[kq * 4 + 3][row] = v.w;
            }
        } else {
            #pragma unroll
            for (int l = 0; l < 2; ++l) {
                int q = tid * 2 + l;
                int krow = q >> 4, nq = q & 15;
                float4 v = *(const float4*)(B + (size_t)(kk + krow) * Ndim + n0 + nq * 4);
                *(float4*)&Bs[krow][nq * 4] = v;
            }
        }
        __syncthreads();
        #pragma unroll
        for (int k = 0; k < 32; ++k) {
            float4 av = *(const float4*)&As[k][ty * 4];
            float4 bv = *(const float4*)&Bs[k][tx * 4];
            acc[0][0] += av.x * bv.x; acc[0][1] += av.x * bv.y; acc[0][2] += av.x * bv.z; acc[0][3] += av.x * bv.w;
            acc[1][0] += av.y * bv.x; acc[1][1] += av.y * bv.y; acc[1][2] += av.y * bv.z; acc[1][3] += av.y * bv.w;
            acc[2][0] += av.z * bv.x; acc[2][1] += av.z * bv.y; acc[2][2] += av.z * bv.z; acc[2][3] += av.z * bv.w;
            acc[3][0] += av.w * bv.x; acc[3][1] += av.w * bv.y; acc[3][2] += av.w * bv.z; acc[3][3] += av.w * bv.w;
        }
        __syncthreads();
    }
    #pragma unroll
    for (int r = 0; r < 4; ++r) {
        int gm = m0 + ty * 4 + r;
        float4 res;
        res.x = alpha * acc[r][0];
        res.y = alpha * acc[r][1];
        res.z = alpha * acc[r][2];
        res.w = alpha * acc[r][3];
        if (Add) {
            float4 ad = *(const float4*)(Add + (size_t)gm * Ndim + n0 + tx * 4);
            res.x += ad.x; res.y += ad.y; res.z += ad.z; res.w += ad.w;
        }
        *(float4*)(C + (size_t)gm * Ndim + n0 + tx * 4) = res;
    }
}

// ---------------------------------------------------------------------------
// Segmented strict prefix-scan: P[t,j] = sum_{s in seg(t), s<t} phi[s,i]*U[s,c]
// (segment-local; global offsets come via S->O and are folded into GEMM A-staging)
// j = i*512 + c. One thread per column, one block-row per segment.
// ---------------------------------------------------------------------------
__global__ __launch_bounds__(256) void scanA(
    const float* __restrict__ U, const float* __restrict__ phi,
    float* __restrict__ P, float* __restrict__ S)
{
    const int j = blockIdx.x * 256 + threadIdx.x;
    const int seg = blockIdx.y;
    const int i = j >> 9;
    const int c = j & 511;
    float acc = 0.f;
    const int t0 = seg * SEGLEN;
    for (int t = t0; t < t0 + SEGLEN; ++t) {
        P[(size_t)t * J_ + j] = acc;
        acc += phi[t * KF_ + i] * U[(size_t)t * MC_ + c];
    }
    S[(size_t)seg * J_ + j] = acc;
}

// Exclusive scan of segment sums -> per-segment offsets O[seg][j]
__global__ __launch_bounds__(256) void scanB(const float* __restrict__ S,
                                             float* __restrict__ O)
{
    const int j = blockIdx.x * 256 + threadIdx.x;
    float off = 0.f;
    #pragma unroll
    for (int s = 0; s < NSEG; ++s) {
        O[(size_t)s * J_ + j] = off;
        off += S[(size_t)s * J_ + j];
    }
}

// ---------------------------------------------------------------------------
// ywE[t, c, i] = sum_n w[t,n] * E[c,n,i]   (E is [MC][N][M] row-major)
// Block: 64 t-rows x 16 c-cols; w staged in LDS, E read via L1 (row reused by 16 threads)
// ---------------------------------------------------------------------------
__global__ __launch_bounds__(256) void build_ywE(
    const float* __restrict__ w, const float* __restrict__ E,
    float* __restrict__ ywE)
{
    __shared__ __align__(16) float Ws[64][36];
    const int tid = threadIdx.x;
    const int c0 = blockIdx.x * 16, t0 = blockIdx.y * 64;
    const int cl = tid & 15, tg = tid >> 4;
    const int c = c0 + cl;
    float acc[4][5] = {};
    for (int n0 = 0; n0 < N_; n0 += 32) {
        #pragma unroll
        for (int l = 0; l < 2; ++l) {
            int q = tid * 2 + l;
            int row = q >> 3, nq = q & 7;
            float4 v = *(const float4*)(w + (size_t)(t0 + row) * N_ + n0 + nq * 4);
            *(float4*)&Ws[row][nq * 4] = v;
        }
        __syncthreads();
        for (int nn = 0; nn < 32; ++nn) {
            const float* ep = E + (size_t)c * (N_ * M_) + (size_t)(n0 + nn) * M_;
            float e0 = ep[0], e1 = ep[1], e2 = ep[2], e3 = ep[3], e4 = ep[4];
            #pragma unroll
            for (int r = 0; r < 4; ++r) {
                float wv = Ws[tg * 4 + r][nn];
                acc[r][0] += wv * e0; acc[r][1] += wv * e1; acc[r][2] += wv * e2;
                acc[r][3] += wv * e3; acc[r][4] += wv * e4;
            }
        }
        __syncthreads();
    }
    #pragma unroll
    for (int r = 0; r < 4; ++r) {
        int t = t0 + tg * 4 + r;
        #pragma unroll
        for (int ii = 0; ii < M_; ++ii)
            ywE[(size_t)t * (MC_ * M_) + (size_t)c * M_ + ii] = acc[r][ii];
    }
}

// D[t,c] = bias[c] + sum_i ywE[t-4+i, c, i]  (zero for t-4+i < 0)
__global__ __launch_bounds__(256) void build_D(
    const float* __restrict__ ywE, const float* __restrict__ bias,
    float* __restrict__ D)
{
    const int idx = blockIdx.x * 256 + threadIdx.x;
    const int t = idx >> 9, c = idx & 511;
    float v = bias[c];
    #pragma unroll
    for (int ii = 0; ii < M_; ++ii) {
        int ts = t - (M_ - 1) + ii;
        if (ts >= 0) v += ywE[(size_t)ts * (MC_ * M_) + c * M_ + ii];
    }
    D[idx] = v;
}

// losses[t] = dot(X[t], Y[t]) + dot(U[t], Z[t])   (Y = X@Q, Z = U@R)
__global__ __launch_bounds__(256) void rowdot(
    const float* __restrict__ X, const float* __restrict__ Y,
    const float* __restrict__ U, const float* __restrict__ Z,
    float* __restrict__ out)
{
    const int t = blockIdx.x;
    float s = 0.f;
    for (int n = threadIdx.x; n < N_; n += 256)
        s += X[(size_t)t * N_ + n] * Y[(size_t)t * N_ + n];
    for (int c = threadIdx.x; c < MC_; c += 256)
        s += U[(size_t)t * MC_ + c] * Z[(size_t)t * MC_ + c];
    __shared__ float red[256];
    red[threadIdx.x] = s;
    __syncthreads();
    for (int off = 128; off > 0; off >>= 1) {
        if (threadIdx.x < off) red[threadIdx.x] += red[threadIdx.x + off];
        __syncthreads();
    }
    if (threadIdx.x == 0) out[t] = red[0];
}

// ---------------------------------------------------------------------------
extern "C" void kernel_launch(void* const* d_in, const int* in_sizes, int n_in,
                              void* d_out, int out_size, void* d_ws, size_t ws_size,
                              hipStream_t stream)
{
    // Inputs (setup_inputs dict order): A, B, Q, R, K, E, bias, E_stu, phi, w_test
    const float* Qm   = (const float*)d_in[2];
    const float* Rm   = (const float*)d_in[3];
    const float* Km   = (const float*)d_in[4];
    const float* Em   = (const float*)d_in[5];
    const float* bias = (const float*)d_in[6];
    const float* Estu = (const float*)d_in[7];   // [KF][MC][N] = flat [J_, N_]
    const float* phi  = (const float*)d_in[8];   // [T, KF]
    const float* w    = (const float*)d_in[9];   // [T, N]
    float* out = (float*)d_out;

    // Workspace layout (fp32), ~135 MB total
    float* ws = (float*)d_ws;
    float* F = ws;                                 // [MC, J]
    float* D = F + (size_t)MC_ * J_;               // [T, MC]
    float* U = D + (size_t)T_ * MC_;               // [T, MC]
    float* P = U + (size_t)T_ * MC_;               // [T, J]
    float* S = P + (size_t)T_ * J_;                // [NSEG, J]
    float* O = S + (size_t)NSEG * J_;              // [NSEG, J]
    float* X = O + (size_t)NSEG * J_;              // [T, N]
    float* Y = X + (size_t)T_ * N_;                // [T, N]
    float* Z = Y + (size_t)T_ * N_;                // [T, MC]
    float* ywE = P;                                // alias: used before P is needed

    dim3 blk(256);

    // F = -K @ Estu^T : [512,1024] x [10240,1024]^T -> [512, 10240]   (NT)
    gemm_f32<1><<<dim3(J_ / 64, MC_ / 64), blk, 0, stream>>>(
        Km, Estu, nullptr, nullptr, F, MC_, J_, N_, -1.0f);

    // D[t,c] = bias[c] + sum_i <w_{t-4+i}, E[c,:,i]>
    build_ywE<<<dim3(MC_ / 16, T_ / 64), blk, 0, stream>>>(w, Em, ywE);
    build_D<<<dim3(T_ * MC_ / 256), blk, 0, stream>>>(ywE, bias, D);

    // U^0 = D
    hipMemcpyAsync(U, D, (size_t)T_ * MC_ * sizeof(float),
                   hipMemcpyDeviceToDevice, stream);

    // Neumann iterations: U <- D + F * prefix(U)
    for (int it = 0; it < NIT; ++it) {
        scanA<<<dim3(J_ / 256, NSEG), blk, 0, stream>>>(U, phi, P, S);
        scanB<<<dim3(J_ / 256), blk, 0, stream>>>(S, O);
        gemm_f32<1><<<dim3(MC_ / 64, T_ / 64), blk, 0, stream>>>(
            P, F, D, O, U, T_, MC_, J_, 1.0f);
    }

    // Final prefix for x, then X = P @ Estu : [2048,10240] x [10240,1024] (NN)
    scanA<<<dim3(J_ / 256, NSEG), blk, 0, stream>>>(U, phi, P, S);
    scanB<<<dim3(J_ / 256), blk, 0, stream>>>(S, O);
    gemm_f32<0><<<dim3(N_ / 64, T_ / 64), blk, 0, stream>>>(
        P, Estu, nullptr, O, X, T_, N_, J_, 1.0f);

    // Y = X @ Q ; Z = U @ R ; losses = rowdot
    gemm_f32<0><<<dim3(N_ / 64, T_ / 64), blk, 0, stream>>>(
        X, Qm, nullptr, nullptr, Y, T_, N_, N_, 1.0f);
    gemm_f32<0><<<dim3(MC_ / 64, T_ / 64), blk, 0, stream>>>(
        U, Rm, nullptr, nullptr, Z, T_, MC_, MC_, 1.0f);
    rowdot<<<dim3(T_), blk, 0, stream>>>(X, Y, U, Z, out);
}

// Round 2
// 994.272 us; speedup vs baseline: 11.0424x; 11.0424x over previous
//
#include <hip/hip_runtime.h>

// Problem constants (fixed by the reference)
#define T_    2048
#define N_    1024
#define MC_   512
#define KF_   20
#define M_    5
#define J_    (KF_ * MC_)      // 10240
#define NSEG  8
#define SEGLEN (T_ / NSEG)     // 256
#define NIT   6                // Neumann iterations (round-1 absmax=0.0 @14 -> big slack)

typedef unsigned short u16;
typedef __attribute__((ext_vector_type(8))) __bf16 bf16v;  // 4 VGPRs, MFMA A/B frag
typedef __attribute__((ext_vector_type(4))) float  f32x4;  // MFMA C/D frag

__device__ inline u16 f2bf(float f) {                      // RNE f32 -> bf16
    unsigned u = __float_as_uint(f);
    u += 0x7fff + ((u >> 16) & 1);
    return (u16)(u >> 16);
}

__device__ inline void gload16(const void* g, void* l) {   // 16B global -> LDS (lane*16 dest)
    __builtin_amdgcn_global_load_lds((const __attribute__((address_space(1))) void*)g,
                                     (__attribute__((address_space(3))) void*)l, 16, 0, 0);
}

// ---------------------------------------------------------------------------
// bf16 MFMA GEMM, TN form: C[m,n] = alpha * sum_k A[m,k]*B[n,k]
// A [M,K] bf16 row-major, B [N,K] bf16 row-major. 128x128 tile, BK=32,
// 4 waves (each a 64x64 quadrant, 4x4 fragments of 16x16x32).
// SPLITK>1: grid.z splits K; partials (alpha applied) to Cp[z]. Reduce adds them.
// SPLITK==1: epilogue adds Add (if set), writes Cf (f32) and/or Cb (bf16).
// ---------------------------------------------------------------------------
template<int SPLITK>
__global__ __launch_bounds__(256) void gemm_tn(
    const u16* __restrict__ A, const u16* __restrict__ B,
    const float* __restrict__ Add, float* __restrict__ Cf,
    u16* __restrict__ Cb, float* __restrict__ Cp,
    int Mdim, int Ndim, int Kdim, float alpha)
{
    __shared__ u16 As[128 * 32];   // [row][k] linear, 8 KB
    __shared__ u16 Bs[128 * 32];
    const int tid = threadIdx.x;
    const int wv = tid >> 6, ln = tid & 63;
    const int wr = wv >> 1, wc = wv & 1;         // wave quadrant
    const int l15 = ln & 15, l4 = ln >> 4;
    const int m0 = blockIdx.y * 128, n0 = blockIdx.x * 128;
    const int Kc = Kdim / SPLITK;
    const int kbeg = blockIdx.z * Kc;

    f32x4 acc[4][4] = {};

    for (int kk = kbeg; kk < kbeg + Kc; kk += 32) {
        // Stage A,B tiles (128 rows x 32 k bf16 = 8KB each) via global_load_lds.
        // Wave wv, round r covers linear elements [((wv*2+r)*64+ln)*8, +8).
        #pragma unroll
        for (int r = 0; r < 2; ++r) {
            const int e = ((wv * 2 + r) * 64 + ln) * 8;
            const int row = e >> 5, kq = e & 31;
            gload16(A + (size_t)(m0 + row) * Kdim + kk + kq, &As[(wv * 2 + r) * 512]);
            gload16(B + (size_t)(n0 + row) * Kdim + kk + kq, &Bs[(wv * 2 + r) * 512]);
        }
        __syncthreads();   // compiler drains vmcnt here
        bf16v a[4], b[4];
        #pragma unroll
        for (int i = 0; i < 4; ++i) {
            a[i] = *(const bf16v*)&As[(wr * 64 + i * 16 + l15) * 32 + l4 * 8];
            b[i] = *(const bf16v*)&Bs[(wc * 64 + i * 16 + l15) * 32 + l4 * 8];
        }
        #pragma unroll
        for (int i = 0; i < 4; ++i)
            #pragma unroll
            for (int j = 0; j < 4; ++j)
                acc[i][j] = __builtin_amdgcn_mfma_f32_16x16x32_bf16(a[i], b[j], acc[i][j], 0, 0, 0);
        __syncthreads();
    }

    // C/D layout: col = lane&15, row = (lane>>4)*4 + reg  [m89-verified]
    #pragma unroll
    for (int i = 0; i < 4; ++i)
        #pragma unroll
        for (int j = 0; j < 4; ++j)
            #pragma unroll
            for (int r = 0; r < 4; ++r) {
                const int gm = m0 + wr * 64 + i * 16 + l4 * 4 + r;
                const int gn = n0 + wc * 64 + j * 16 + l15;
                const size_t off = (size_t)gm * Ndim + gn;
                float v = alpha * acc[i][j][r];
                if (SPLITK > 1) {
                    Cp[(size_t)blockIdx.z * Mdim * Ndim + off] = v;
                } else {
                    if (Add) v += Add[off];
                    if (Cf) Cf[off] = v;
                    if (Cb) Cb[off] = f2bf(v);
                }
            }
}

// Sum split-K partials (+Add), write f32 and/or bf16
__global__ __launch_bounds__(256) void reduce_k(
    const float* __restrict__ Cp, int nz, int sz,
    const float* __restrict__ Add, float* __restrict__ Cf, u16* __restrict__ Cb)
{
    const size_t i = ((size_t)blockIdx.x * 256 + threadIdx.x) * 4;
    float4 s = {0.f, 0.f, 0.f, 0.f};
    for (int z = 0; z < nz; ++z) {
        float4 v = *(const float4*)(Cp + (size_t)z * sz + i);
        s.x += v.x; s.y += v.y; s.z += v.z; s.w += v.w;
    }
    if (Add) {
        float4 a = *(const float4*)(Add + i);
        s.x += a.x; s.y += a.y; s.z += a.z; s.w += a.w;
    }
    if (Cf) *(float4*)(Cf + i) = s;
    if (Cb) {
        ushort4 o; o.x = f2bf(s.x); o.y = f2bf(s.y); o.z = f2bf(s.z); o.w = f2bf(s.w);
        *(ushort4*)(Cb + i) = o;
    }
}

// fp32 -> bf16 cast (n4 = n/4 float4 groups)
__global__ __launch_bounds__(256) void cast_bf(const float* __restrict__ in,
                                               u16* __restrict__ out, int n4)
{
    const int i = blockIdx.x * 256 + threadIdx.x;
    if (i >= n4) return;
    float4 v = *(const float4*)(in + (size_t)i * 4);
    ushort4 o; o.x = f2bf(v.x); o.y = f2bf(v.y); o.z = f2bf(v.z); o.w = f2bf(v.w);
    *(ushort4*)(out + (size_t)i * 4) = o;
}

// EstuT[n][j] = Estu[j][n], fp32 -> bf16 (32x32 LDS tile)
__global__ __launch_bounds__(256) void transpose_bf(const float* __restrict__ in,
                                                    u16* __restrict__ out)
{
    __shared__ float tile[32][33];
    const int j0 = blockIdx.x * 32, n0 = blockIdx.y * 32;
    const int tx = threadIdx.x & 31, ty = threadIdx.x >> 5;
    #pragma unroll
    for (int r = 0; r < 4; ++r)
        tile[ty + r * 8][tx] = in[(size_t)(j0 + ty + r * 8) * N_ + n0 + tx];
    __syncthreads();
    #pragma unroll
    for (int r = 0; r < 4; ++r)
        out[(size_t)(n0 + ty + r * 8) * J_ + j0 + tx] = f2bf(tile[tx][ty + r * 8]);
}

// EbT[(c*5+ii)][n] = E[c][n][ii]  bf16  (B-operand for the ywE GEMM)
__global__ __launch_bounds__(256) void build_EbT(const float* __restrict__ E,
                                                 u16* __restrict__ EbT)
{
    const int c = blockIdx.x;
    for (int n = threadIdx.x; n < N_; n += 256) {
        const float* ep = E + (size_t)c * (N_ * M_) + (size_t)n * M_;
        #pragma unroll
        for (int ii = 0; ii < M_; ++ii)
            EbT[(size_t)(c * M_ + ii) * N_ + n] = f2bf(ep[ii]);
    }
}

// Pass 1: segment sums S[seg][j] = sum_{t in seg} phi[t,i]*U[t,c],  j=i*512+c
__global__ __launch_bounds__(256) void scanS(const float* __restrict__ U,
                                             const float* __restrict__ phi,
                                             float* __restrict__ S)
{
    const int j = blockIdx.x * 256 + threadIdx.x;
    const int seg = blockIdx.y;
    const int i = j >> 9, c = j & 511;
    float acc = 0.f;
    const int t0 = seg * SEGLEN;
    for (int t = t0; t < t0 + SEGLEN; ++t)
        acc += phi[t * KF_ + i] * U[(size_t)t * MC_ + c];
    S[(size_t)seg * J_ + j] = acc;
}

// Pass 2: exclusive scan over segments
__global__ __launch_bounds__(256) void scanB(const float* __restrict__ S,
                                             float* __restrict__ O)
{
    const int j = blockIdx.x * 256 + threadIdx.x;
    float off = 0.f;
    #pragma unroll
    for (int s = 0; s < NSEG; ++s) {
        O[(size_t)s * J_ + j] = off;
        off += S[(size_t)s * J_ + j];
    }
}

// Pass 3: global strict prefix, written directly as bf16 P
__global__ __launch_bounds__(256) void scanC(const float* __restrict__ U,
                                             const float* __restrict__ phi,
                                             const float* __restrict__ O,
                                             u16* __restrict__ P)
{
    const int j = blockIdx.x * 256 + threadIdx.x;
    const int seg = blockIdx.y;
    const int i = j >> 9, c = j & 511;
    float acc = O[(size_t)seg * J_ + j];
    const int t0 = seg * SEGLEN;
    for (int t = t0; t < t0 + SEGLEN; ++t) {
        P[(size_t)t * J_ + j] = f2bf(acc);
        acc += phi[t * KF_ + i] * U[(size_t)t * MC_ + c];
    }
}

// D[t,c] = bias[c] + sum_i ywE[t-4+i][c*5+i]
__global__ __launch_bounds__(256) void build_D(const float* __restrict__ ywE,
                                               const float* __restrict__ bias,
                                               float* __restrict__ D)
{
    const int idx = blockIdx.x * 256 + threadIdx.x;
    const int t = idx >> 9, c = idx & 511;
    float v = bias[c];
    #pragma unroll
    for (int ii = 0; ii < M_; ++ii) {
        int ts = t - (M_ - 1) + ii;
        if (ts >= 0) v += ywE[(size_t)ts * (MC_ * M_) + c * M_ + ii];
    }
    D[idx] = v;
}

// losses[t] = dot(X[t],Y[t]) + dot(U[t],Z[t])
__global__ __launch_bounds__(256) void rowdot(
    const float* __restrict__ X, const float* __restrict__ Y,
    const float* __restrict__ U, const float* __restrict__ Z,
    float* __restrict__ out)
{
    const int t = blockIdx.x;
    float s = 0.f;
    for (int n = threadIdx.x; n < N_; n += 256)
        s += X[(size_t)t * N_ + n] * Y[(size_t)t * N_ + n];
    for (int c = threadIdx.x; c < MC_; c += 256)
        s += U[(size_t)t * MC_ + c] * Z[(size_t)t * MC_ + c];
    __shared__ float red[256];
    red[threadIdx.x] = s;
    __syncthreads();
    for (int off = 128; off > 0; off >>= 1) {
        if (threadIdx.x < off) red[threadIdx.x] += red[threadIdx.x + off];
        __syncthreads();
    }
    if (threadIdx.x == 0) out[t] = red[0];
}

// ---------------------------------------------------------------------------
extern "C" void kernel_launch(void* const* d_in, const int* in_sizes, int n_in,
                              void* d_out, int out_size, void* d_ws, size_t ws_size,
                              hipStream_t stream)
{
    const float* Qm   = (const float*)d_in[2];
    const float* Rm   = (const float*)d_in[3];
    const float* Km   = (const float*)d_in[4];
    const float* Em   = (const float*)d_in[5];
    const float* bias = (const float*)d_in[6];
    const float* Estu = (const float*)d_in[7];   // [J_, N_]
    const float* phi  = (const float*)d_in[8];   // [T, KF]
    const float* w    = (const float*)d_in[9];   // [T, N]
    float* out = (float*)d_out;

    // ---- workspace carve-up (~131 MB; round-1 used 134.9 MB OK) ----
    char* w8 = (char*)d_ws;
    size_t off = 0;
    auto alloc = [&](size_t bytes) -> void* {
        void* p = w8 + off; off += (bytes + 255) & ~(size_t)255; return p;
    };
    u16*   Pb  = (u16*)  alloc((size_t)T_ * J_ * 2);        // bf16 prefix P (42 MB)
    u16*   Fb  = (u16*)  alloc((size_t)MC_ * J_ * 2);       // bf16 F
    float* D   = (float*)alloc((size_t)T_ * MC_ * 4);
    float* U   = (float*)alloc((size_t)T_ * MC_ * 4);
    u16*   Ub  = (u16*)  alloc((size_t)T_ * MC_ * 2);
    float* S   = (float*)alloc((size_t)NSEG * J_ * 4);
    float* O   = (float*)alloc((size_t)NSEG * J_ * 4);
    float* X   = (float*)alloc((size_t)T_ * N_ * 4);
    u16*   Xb  = (u16*)  alloc((size_t)T_ * N_ * 2);
    float* scr = (float*)alloc((size_t)T_ * (MC_ * M_) * 4); // 21 MB: ywE, then split-K partials
    u16*   Eb  = (u16*)  alloc((size_t)J_ * N_ * 2);         // Estu cast, later overwritten by EstuT
    u16*   EbT = (u16*)  alloc((size_t)(MC_ * M_) * N_ * 2);
    u16*   Kb  = (u16*)  alloc((size_t)MC_ * N_ * 2);
    u16*   Qb  = (u16*)  alloc((size_t)N_ * N_ * 2);
    u16*   Rb  = (u16*)  alloc((size_t)MC_ * MC_ * 2);
    u16*   Wb  = (u16*)  alloc((size_t)T_ * N_ * 2);
    float* Y   = (float*)Pb;                                  // aliases: P dead by then
    float* Z   = (float*)((char*)Pb + (size_t)T_ * N_ * 4);

    dim3 blk(256);

    // Casts to bf16
    cast_bf<<<dim3(MC_ * N_ / 1024), blk, 0, stream>>>(Km, Kb, MC_ * N_ / 4);
    cast_bf<<<dim3(N_ * N_ / 1024), blk, 0, stream>>>(Qm, Qb, N_ * N_ / 4);
    cast_bf<<<dim3(MC_ * MC_ / 1024), blk, 0, stream>>>(Rm, Rb, MC_ * MC_ / 4);
    cast_bf<<<dim3(T_ * N_ / 1024), blk, 0, stream>>>(w, Wb, T_ * N_ / 4);
    cast_bf<<<dim3(J_ * N_ / 1024), blk, 0, stream>>>(Estu, Eb, J_ * N_ / 4);
    build_EbT<<<dim3(MC_), blk, 0, stream>>>(Em, EbT);

    // F = -K @ Estu^T  -> bf16 [MC_, J_]
    gemm_tn<1><<<dim3(J_ / 128, MC_ / 128, 1), blk, 0, stream>>>(
        Kb, Eb, nullptr, nullptr, Fb, nullptr, MC_, J_, N_, -1.0f);

    // ywE[t][c*5+ii] = sum_n w[t,n]*E[c,n,ii]  -> scr (f32)
    gemm_tn<1><<<dim3((MC_ * M_) / 128, T_ / 128, 1), blk, 0, stream>>>(
        Wb, EbT, nullptr, scr, nullptr, nullptr, T_, MC_ * M_, N_, 1.0f);
    build_D<<<dim3(T_ * MC_ / 256), blk, 0, stream>>>(scr, bias, D);

    // U^0 = D
    hipMemcpyAsync(U, D, (size_t)T_ * MC_ * sizeof(float),
                   hipMemcpyDeviceToDevice, stream);

    // EstuT overwrites Eb (safe: F-GEMM ordered before on stream)
    transpose_bf<<<dim3(J_ / 32, N_ / 32), blk, 0, stream>>>(Estu, Eb);

    // Neumann iterations: U <- D + F * prefix(U)
    for (int it = 0; it < NIT; ++it) {
        scanS<<<dim3(J_ / 256, NSEG), blk, 0, stream>>>(U, phi, S);
        scanB<<<dim3(J_ / 256), blk, 0, stream>>>(S, O);
        scanC<<<dim3(J_ / 256, NSEG), blk, 0, stream>>>(U, phi, O, Pb);
        gemm_tn<4><<<dim3(MC_ / 128, T_ / 128, 4), blk, 0, stream>>>(
            Pb, Fb, nullptr, nullptr, nullptr, scr, T_, MC_, J_, 1.0f);
        reduce_k<<<dim3(T_ * MC_ / 1024), blk, 0, stream>>>(
            scr, 4, T_ * MC_, D, U, (it == NIT - 1) ? Ub : nullptr);
    }

    // Final prefix, then X = P @ Estu
    scanS<<<dim3(J_ / 256, NSEG), blk, 0, stream>>>(U, phi, S);
    scanB<<<dim3(J_ / 256), blk, 0, stream>>>(S, O);
    scanC<<<dim3(J_ / 256, NSEG), blk, 0, stream>>>(U, phi, O, Pb);
    gemm_tn<2><<<dim3(N_ / 128, T_ / 128, 2), blk, 0, stream>>>(
        Pb, Eb, nullptr, nullptr, nullptr, scr, T_, N_, J_, 1.0f);
    reduce_k<<<dim3(T_ * N_ / 1024), blk, 0, stream>>>(scr, 2, T_ * N_, nullptr, X, Xb);

    // Y = X @ Q (symmetric) ; Z = U @ R (symmetric) ; losses
    gemm_tn<2><<<dim3(N_ / 128, T_ / 128, 2), blk, 0, stream>>>(
        Xb, Qb, nullptr, nullptr, nullptr, scr, T_, N_, N_, 1.0f);
    reduce_k<<<dim3(T_ * N_ / 1024), blk, 0, stream>>>(scr, 2, T_ * N_, nullptr, Y, nullptr);
    gemm_tn<4><<<dim3(MC_ / 128, T_ / 128, 4), blk, 0, stream>>>(
        Ub, Rb, nullptr, nullptr, nullptr, scr, T_, MC_, MC_, 1.0f);
    reduce_k<<<dim3(T_ * MC_ / 1024), blk, 0, stream>>>(scr, 4, T_ * MC_, nullptr, Z, nullptr);
    rowdot<<<dim3(T_), blk, 0, stream>>>(X, Y, U, Z, out);
}

// Round 3
// 742.215 us; speedup vs baseline: 14.7924x; 1.3396x over previous
//
#include <hip/hip_runtime.h>

// Problem constants (fixed by the reference)
#define T_    2048
#define N_    1024
#define MC_   512
#define KF_   20
#define M_    5
#define J_    (KF_ * MC_)      // 10240
#define NSEG  8
#define SEGLEN (T_ / NSEG)     // 256
#define NIT   4                // Neumann iterations (absmax@6 == bf16 noise -> trim)

typedef unsigned short u16;
typedef __attribute__((ext_vector_type(8))) __bf16 bf16v;  // 4 VGPRs, MFMA A/B frag
typedef __attribute__((ext_vector_type(4))) float  f32x4;  // MFMA C/D frag

__device__ inline u16 f2bf(float f) {                      // RNE f32 -> bf16
    unsigned u = __float_as_uint(f);
    u += 0x7fff + ((u >> 16) & 1);
    return (u16)(u >> 16);
}

__device__ inline void gload16(const void* g, void* l) {   // 16B global -> LDS (lane*16 dest)
    __builtin_amdgcn_global_load_lds((const __attribute__((address_space(1))) void*)g,
                                     (__attribute__((address_space(3))) void*)l, 16, 0, 0);
}

// ---------------------------------------------------------------------------
// bf16 MFMA GEMM, TN form: C[m,n] = alpha * sum_k A[m,k]*B[n,k]
// A [M,K] bf16 row-major, B [N,K] bf16 row-major. 128x128 tile, BK=32,
// 4 waves (each a 64x64 quadrant, 4x4 fragments of 16x16x32).
// nz>1 (Cp set): grid.z splits K; partials (alpha applied) go to Cp[z].
// nz==1: epilogue adds Add (if set), writes Cf (f32) and/or Cb (bf16).
// Block ids are chunk-swizzled across the 8 XCDs (bijective; total%8==0
// for every launch) with orientation chosen so blocks sharing an operand
// panel land in the same XCD's L2.
// ---------------------------------------------------------------------------
__global__ __launch_bounds__(256) void gemm_tn(
    const u16* __restrict__ A, const u16* __restrict__ B,
    const float* __restrict__ Add, float* __restrict__ Cf,
    u16* __restrict__ Cb, float* __restrict__ Cp,
    int Mdim, int Ndim, int Kdim, float alpha)
{
    __shared__ u16 As[128 * 32];   // [row][k] linear, 8 KB
    __shared__ u16 Bs[128 * 32];

    // ---- XCD chunk swizzle (T1, bijective since total%8==0) ----
    const int gx = gridDim.x, gy = gridDim.y;
    const int total = gx * gy * gridDim.z;
    int lin = blockIdx.x + gx * (blockIdx.y + gy * blockIdx.z);
    lin = (lin & 7) * (total >> 3) + (lin >> 3);
    int bx, by, bz;
    if (gx <= gy) { bx = lin % gx; int r = lin / gx; by = r % gy; bz = r / gy; }
    else          { by = lin % gy; int r = lin / gy; bx = r % gx; bz = r / gx; }

    const int tid = threadIdx.x;
    const int wv = tid >> 6, ln = tid & 63;
    const int wr = wv >> 1, wc = wv & 1;         // wave quadrant
    const int l15 = ln & 15, l4 = ln >> 4;
    const int m0 = by * 128, n0 = bx * 128;
    const int Kc = Kdim / gridDim.z;
    const int kbeg = bz * Kc;

    f32x4 acc[4][4] = {};

    for (int kk = kbeg; kk < kbeg + Kc; kk += 32) {
        // Stage A,B tiles (128 rows x 32 k bf16 = 8KB each) via global_load_lds.
        #pragma unroll
        for (int r = 0; r < 2; ++r) {
            const int e = ((wv * 2 + r) * 64 + ln) * 8;
            const int row = e >> 5, kq = e & 31;
            gload16(A + (size_t)(m0 + row) * Kdim + kk + kq, &As[(wv * 2 + r) * 512]);
            gload16(B + (size_t)(n0 + row) * Kdim + kk + kq, &Bs[(wv * 2 + r) * 512]);
        }
        __syncthreads();   // compiler drains vmcnt here
        bf16v a[4], b[4];
        #pragma unroll
        for (int i = 0; i < 4; ++i) {
            a[i] = *(const bf16v*)&As[(wr * 64 + i * 16 + l15) * 32 + l4 * 8];
            b[i] = *(const bf16v*)&Bs[(wc * 64 + i * 16 + l15) * 32 + l4 * 8];
        }
        #pragma unroll
        for (int i = 0; i < 4; ++i)
            #pragma unroll
            for (int j = 0; j < 4; ++j)
                acc[i][j] = __builtin_amdgcn_mfma_f32_16x16x32_bf16(a[i], b[j], acc[i][j], 0, 0, 0);
        __syncthreads();
    }

    // C/D layout: col = lane&15, row = (lane>>4)*4 + reg  [m89-verified]
    #pragma unroll
    for (int i = 0; i < 4; ++i)
        #pragma unroll
        for (int j = 0; j < 4; ++j)
            #pragma unroll
            for (int r = 0; r < 4; ++r) {
                const int gm = m0 + wr * 64 + i * 16 + l4 * 4 + r;
                const int gn = n0 + wc * 64 + j * 16 + l15;
                const size_t off = (size_t)gm * Ndim + gn;
                float v = alpha * acc[i][j][r];
                if (Cp) {
                    Cp[(size_t)bz * Mdim * Ndim + off] = v;
                } else {
                    if (Add) v += Add[off];
                    if (Cf) Cf[off] = v;
                    if (Cb) Cb[off] = f2bf(v);
                }
            }
}

// Sum split-K partials (+Add), write f32 and/or bf16
__global__ __launch_bounds__(256) void reduce_k(
    const float* __restrict__ Cp, int nz, int sz,
    const float* __restrict__ Add, float* __restrict__ Cf, u16* __restrict__ Cb)
{
    const size_t i = ((size_t)blockIdx.x * 256 + threadIdx.x) * 4;
    float4 s = {0.f, 0.f, 0.f, 0.f};
    for (int z = 0; z < nz; ++z) {
        float4 v = *(const float4*)(Cp + (size_t)z * sz + i);
        s.x += v.x; s.y += v.y; s.z += v.z; s.w += v.w;
    }
    if (Add) {
        float4 a = *(const float4*)(Add + i);
        s.x += a.x; s.y += a.y; s.z += a.z; s.w += a.w;
    }
    if (Cf) *(float4*)(Cf + i) = s;
    if (Cb) {
        ushort4 o; o.x = f2bf(s.x); o.y = f2bf(s.y); o.z = f2bf(s.z); o.w = f2bf(s.w);
        *(ushort4*)(Cb + i) = o;
    }
}

// fp32 -> bf16 cast (n4 = n/4 float4 groups)
__global__ __launch_bounds__(256) void cast_bf(const float* __restrict__ in,
                                               u16* __restrict__ out, int n4)
{
    const int i = blockIdx.x * 256 + threadIdx.x;
    if (i >= n4) return;
    float4 v = *(const float4*)(in + (size_t)i * 4);
    ushort4 o; o.x = f2bf(v.x); o.y = f2bf(v.y); o.z = f2bf(v.z); o.w = f2bf(v.w);
    *(ushort4*)(out + (size_t)i * 4) = o;
}

// EstuT[n][j] = Estu[j][n], fp32 -> bf16 (32x32 LDS tile)
__global__ __launch_bounds__(256) void transpose_bf(const float* __restrict__ in,
                                                    u16* __restrict__ out)
{
    __shared__ float tile[32][33];
    const int j0 = blockIdx.x * 32, n0 = blockIdx.y * 32;
    const int tx = threadIdx.x & 31, ty = threadIdx.x >> 5;
    #pragma unroll
    for (int r = 0; r < 4; ++r)
        tile[ty + r * 8][tx] = in[(size_t)(j0 + ty + r * 8) * N_ + n0 + tx];
    __syncthreads();
    #pragma unroll
    for (int r = 0; r < 4; ++r)
        out[(size_t)(n0 + ty + r * 8) * J_ + j0 + tx] = f2bf(tile[tx][ty + r * 8]);
}

// EbT[(c*5+ii)][n] = E[c][n][ii]  bf16  (B-operand for the ywE GEMM)
__global__ __launch_bounds__(256) void build_EbT(const float* __restrict__ E,
                                                 u16* __restrict__ EbT)
{
    const int c = blockIdx.x;
    for (int n = threadIdx.x; n < N_; n += 256) {
        const float* ep = E + (size_t)c * (N_ * M_) + (size_t)n * M_;
        #pragma unroll
        for (int ii = 0; ii < M_; ++ii)
            EbT[(size_t)(c * M_ + ii) * N_ + n] = f2bf(ep[ii]);
    }
}

// Pass 1: segment sums S[seg][j] = sum_{t in seg} phi[t,i]*U[t,c],  j=i*512+c
// (2 j per thread; both share i since j0 is even within a 512-aligned group)
__global__ __launch_bounds__(256) void scanS(const float* __restrict__ U,
                                             const float* __restrict__ phi,
                                             float* __restrict__ S)
{
    const int j0 = (blockIdx.x * 256 + threadIdx.x) * 2;
    const int seg = blockIdx.y;
    const int i = j0 >> 9, c = j0 & 511;
    float a0 = 0.f, a1 = 0.f;
    const int t0 = seg * SEGLEN;
    for (int t = t0; t < t0 + SEGLEN; ++t) {
        float2 u = *(const float2*)(U + (size_t)t * MC_ + c);
        float ph = phi[t * KF_ + i];
        a0 += ph * u.x; a1 += ph * u.y;
    }
    *(float2*)(S + (size_t)seg * J_ + j0) = make_float2(a0, a1);
}

// Pass 2: exclusive scan over segments (2 j per thread)
__global__ __launch_bounds__(256) void scanB(const float* __restrict__ S,
                                             float* __restrict__ O)
{
    const int j0 = (blockIdx.x * 256 + threadIdx.x) * 2;
    float o0 = 0.f, o1 = 0.f;
    #pragma unroll
    for (int s = 0; s < NSEG; ++s) {
        *(float2*)(O + (size_t)s * J_ + j0) = make_float2(o0, o1);
        float2 sv = *(const float2*)(S + (size_t)s * J_ + j0);
        o0 += sv.x; o1 += sv.y;
    }
}

// Pass 3: global strict prefix, written directly as bf16 P (2 j per thread)
__global__ __launch_bounds__(256) void scanC(const float* __restrict__ U,
                                             const float* __restrict__ phi,
                                             const float* __restrict__ O,
                                             u16* __restrict__ P)
{
    const int j0 = (blockIdx.x * 256 + threadIdx.x) * 2;
    const int seg = blockIdx.y;
    const int i = j0 >> 9, c = j0 & 511;
    float2 o = *(const float2*)(O + (size_t)seg * J_ + j0);
    float a0 = o.x, a1 = o.y;
    const int t0 = seg * SEGLEN;
    for (int t = t0; t < t0 + SEGLEN; ++t) {
        ushort2 pv; pv.x = f2bf(a0); pv.y = f2bf(a1);
        *(ushort2*)(P + (size_t)t * J_ + j0) = pv;
        float2 u = *(const float2*)(U + (size_t)t * MC_ + c);
        float ph = phi[t * KF_ + i];
        a0 += ph * u.x; a1 += ph * u.y;
    }
}

// D[t,c] = bias[c] + sum_i ywE[t-4+i][c*5+i]
__global__ __launch_bounds__(256) void build_D(const float* __restrict__ ywE,
                                               const float* __restrict__ bias,
                                               float* __restrict__ D)
{
    const int idx = blockIdx.x * 256 + threadIdx.x;
    const int t = idx >> 9, c = idx & 511;
    float v = bias[c];
    #pragma unroll
    for (int ii = 0; ii < M_; ++ii) {
        int ts = t - (M_ - 1) + ii;
        if (ts >= 0) v += ywE[(size_t)ts * (MC_ * M_) + c * M_ + ii];
    }
    D[idx] = v;
}

// losses[t] = dot(X[t],Y[t]) + dot(U[t],Z[t])
__global__ __launch_bounds__(256) void rowdot(
    const float* __restrict__ X, const float* __restrict__ Y,
    const float* __restrict__ U, const float* __restrict__ Z,
    float* __restrict__ out)
{
    const int t = blockIdx.x;
    float s = 0.f;
    for (int n = threadIdx.x; n < N_; n += 256)
        s += X[(size_t)t * N_ + n] * Y[(size_t)t * N_ + n];
    for (int c = threadIdx.x; c < MC_; c += 256)
        s += U[(size_t)t * MC_ + c] * Z[(size_t)t * MC_ + c];
    __shared__ float red[256];
    red[threadIdx.x] = s;
    __syncthreads();
    for (int off = 128; off > 0; off >>= 1) {
        if (threadIdx.x < off) red[threadIdx.x] += red[threadIdx.x + off];
        __syncthreads();
    }
    if (threadIdx.x == 0) out[t] = red[0];
}

// ---------------------------------------------------------------------------
extern "C" void kernel_launch(void* const* d_in, const int* in_sizes, int n_in,
                              void* d_out, int out_size, void* d_ws, size_t ws_size,
                              hipStream_t stream)
{
    const float* Qm   = (const float*)d_in[2];
    const float* Rm   = (const float*)d_in[3];
    const float* Km   = (const float*)d_in[4];
    const float* Em   = (const float*)d_in[5];
    const float* bias = (const float*)d_in[6];
    const float* Estu = (const float*)d_in[7];   // [J_, N_]
    const float* phi  = (const float*)d_in[8];   // [T, KF]
    const float* w    = (const float*)d_in[9];   // [T, N]
    float* out = (float*)d_out;

    // ---- workspace carve-up: 99.7 MB persistent + 33.6 MB transient = 133.3 MB
    // (round-1 proved ws_size >= 134.87 MB)
    char* w8 = (char*)d_ws;
    size_t off = 0;
    auto alloc = [&](size_t bytes) -> void* {
        void* p = w8 + off; off += (bytes + 255) & ~(size_t)255; return p;
    };
    // persistent
    u16*   Pb  = (u16*)  alloc((size_t)T_ * J_ * 2);        // 41.9 MB bf16 prefix P
    u16*   Fb  = (u16*)  alloc((size_t)MC_ * J_ * 2);       // 10.5 MB bf16 F
    float* D   = (float*)alloc((size_t)T_ * MC_ * 4);
    float* U   = (float*)alloc((size_t)T_ * MC_ * 4);
    u16*   Ub  = (u16*)  alloc((size_t)T_ * MC_ * 2);
    float* S   = (float*)alloc((size_t)NSEG * J_ * 4);
    float* O   = (float*)alloc((size_t)NSEG * J_ * 4);
    float* X   = (float*)alloc((size_t)T_ * N_ * 4);
    u16*   Xb  = (u16*)  alloc((size_t)T_ * N_ * 2);
    u16*   Eb  = (u16*)  alloc((size_t)J_ * N_ * 2);        // Estu cast, then EstuT
    u16*   Qb  = (u16*)  alloc((size_t)N_ * N_ * 2);
    u16*   Rb  = (u16*)  alloc((size_t)MC_ * MC_ * 2);
    // transient region B (33.55 MB): phase 1 = {ywE, EbT, Kb, Wb}; later = split-K partials
    char*  regB = (char*)alloc((size_t)4 * T_ * N_ * 4);    // 33,554,432 B
    float* ywE = (float*)regB;                               // 21.0 MB
    u16*   EbT = (u16*)  (regB + 20971520);                  //  5.2 MB
    u16*   Kb  = (u16*)  (regB + 20971520 + 5242880);        //  1.0 MB
    u16*   Wb  = (u16*)  (regB + 20971520 + 5242880 + 1048576); // 4.2 MB
    float* Cp  = (float*)regB;                               // partials (after phase 1)
    float* Y   = (float*)Pb;                                 // aliases: Pb dead by then
    float* Z   = (float*)((char*)Pb + (size_t)T_ * N_ * 4);

    dim3 blk(256);

    // Casts to bf16
    cast_bf<<<dim3(MC_ * N_ / 1024), blk, 0, stream>>>(Km, Kb, MC_ * N_ / 4);
    cast_bf<<<dim3(N_ * N_ / 1024), blk, 0, stream>>>(Qm, Qb, N_ * N_ / 4);
    cast_bf<<<dim3(MC_ * MC_ / 1024), blk, 0, stream>>>(Rm, Rb, MC_ * MC_ / 4);
    cast_bf<<<dim3(T_ * N_ / 1024), blk, 0, stream>>>(w, Wb, T_ * N_ / 4);
    cast_bf<<<dim3(J_ * N_ / 1024), blk, 0, stream>>>(Estu, Eb, J_ * N_ / 4);
    build_EbT<<<dim3(MC_), blk, 0, stream>>>(Em, EbT);

    // F = -K @ Estu^T  -> bf16 [MC_, J_]   (grid 80x4, total 320 %8==0)
    gemm_tn<<<dim3(J_ / 128, MC_ / 128, 1), blk, 0, stream>>>(
        Kb, Eb, nullptr, nullptr, Fb, nullptr, MC_, J_, N_, -1.0f);

    // ywE[t][c*5+ii] = sum_n w[t,n]*E[c,n,ii]  (grid 20x16, total 320)
    gemm_tn<<<dim3((MC_ * M_) / 128, T_ / 128, 1), blk, 0, stream>>>(
        Wb, EbT, nullptr, ywE, nullptr, nullptr, T_, MC_ * M_, N_, 1.0f);
    build_D<<<dim3(T_ * MC_ / 256), blk, 0, stream>>>(ywE, bias, D);

    // U^0 = D
    hipMemcpyAsync(U, D, (size_t)T_ * MC_ * sizeof(float),
                   hipMemcpyDeviceToDevice, stream);

    // EstuT overwrites Eb (safe: F-GEMM ordered before on stream)
    transpose_bf<<<dim3(J_ / 32, N_ / 32), blk, 0, stream>>>(Estu, Eb);

    // Neumann iterations: U <- D + F * prefix(U).  GEMM z=8 -> 512 blocks (2/CU)
    for (int it = 0; it < NIT; ++it) {
        scanS<<<dim3(J_ / 512, NSEG), blk, 0, stream>>>(U, phi, S);
        scanB<<<dim3(J_ / 512), blk, 0, stream>>>(S, O);
        scanC<<<dim3(J_ / 512, NSEG), blk, 0, stream>>>(U, phi, O, Pb);
        gemm_tn<<<dim3(MC_ / 128, T_ / 128, 8), blk, 0, stream>>>(
            Pb, Fb, nullptr, nullptr, nullptr, Cp, T_, MC_, J_, 1.0f);
        reduce_k<<<dim3(T_ * MC_ / 1024), blk, 0, stream>>>(
            Cp, 8, T_ * MC_, D, U, (it == NIT - 1) ? Ub : nullptr);
    }

    // Final prefix, then X = P @ Estu  (z=4 -> 512 blocks)
    scanS<<<dim3(J_ / 512, NSEG), blk, 0, stream>>>(U, phi, S);
    scanB<<<dim3(J_ / 512), blk, 0, stream>>>(S, O);
    scanC<<<dim3(J_ / 512, NSEG), blk, 0, stream>>>(U, phi, O, Pb);
    gemm_tn<<<dim3(N_ / 128, T_ / 128, 4), blk, 0, stream>>>(
        Pb, Eb, nullptr, nullptr, nullptr, Cp, T_, N_, J_, 1.0f);
    reduce_k<<<dim3(T_ * N_ / 1024), blk, 0, stream>>>(Cp, 4, T_ * N_, nullptr, X, Xb);

    // Y = X @ Q (symmetric, z=4) ; Z = U @ R (symmetric, z=4) ; losses
    gemm_tn<<<dim3(N_ / 128, T_ / 128, 4), blk, 0, stream>>>(
        Xb, Qb, nullptr, nullptr, nullptr, Cp, T_, N_, N_, 1.0f);
    reduce_k<<<dim3(T_ * N_ / 1024), blk, 0, stream>>>(Cp, 4, T_ * N_, nullptr, Y, nullptr);
    gemm_tn<<<dim3(MC_ / 128, T_ / 128, 4), blk, 0, stream>>>(
        Ub, Rb, nullptr, nullptr, nullptr, Cp, T_, MC_, MC_, 1.0f);
    reduce_k<<<dim3(T_ * MC_ / 1024), blk, 0, stream>>>(Cp, 4, T_ * MC_, nullptr, Z, nullptr);
    rowdot<<<dim3(T_), blk, 0, stream>>>(X, Y, U, Z, out);
}

// Round 4
// 569.607 us; speedup vs baseline: 19.2750x; 1.3030x over previous
//
#include <hip/hip_runtime.h>

// Problem constants (fixed by the reference)
#define T_    2048
#define N_    1024
#define MC_   512
#define KF_   20
#define M_    5
#define J_    (KF_ * MC_)      // 10240
#define NSEG  8
#define SEGLEN (T_ / NSEG)     // 256
#define NIT   3                // Neumann iterations (absmax flat at 4 & 6 -> trim; ||L||~0.03)

typedef unsigned short u16;
typedef __attribute__((ext_vector_type(8))) __bf16 bf16v;  // 4 VGPRs, MFMA A/B frag
typedef __attribute__((ext_vector_type(4))) float  f32x4;  // MFMA C/D frag

__device__ inline u16 f2bf(float f) {                      // RNE f32 -> bf16
    unsigned u = __float_as_uint(f);
    u += 0x7fff + ((u >> 16) & 1);
    return (u16)(u >> 16);
}

__device__ inline void gload16(const void* g, void* l) {   // 16B global -> LDS (lane*16 dest)
    __builtin_amdgcn_global_load_lds((const __attribute__((address_space(1))) void*)g,
                                     (__attribute__((address_space(3))) void*)l, 16, 0, 0);
}

// ---------------------------------------------------------------------------
// bf16 MFMA GEMM, TN form: C[m,n] = alpha * sum_k A[m,k]*B[n,k]
// A [M,K] bf16 row-major, B [N,K] bf16 row-major. 128x128 tile, BK=32,
// 4 waves (each a 64x64 quadrant, 4x4 fragments of 16x16x32).
// DOUBLE-BUFFERED: next tile's global_load_lds issued before current tile's
// compute; single __syncthreads per K-step (compiler drains vmcnt+lgkmcnt at
// the barrier -> staging complete & all reads of buf done; race-free by
// construction, no manual waitcnt).
// Cp set: grid.z splits K; partials (alpha applied) go to Cp[z].
// else: epilogue adds Add (if set), writes Cf (f32) and/or Cb (bf16).
// Block ids chunk-swizzled across 8 XCDs (bijective; total%8==0 always here).
// ---------------------------------------------------------------------------
__global__ __launch_bounds__(256) void gemm_tn(
    const u16* __restrict__ A, const u16* __restrict__ B,
    const float* __restrict__ Add, float* __restrict__ Cf,
    u16* __restrict__ Cb, float* __restrict__ Cp,
    int Mdim, int Ndim, int Kdim, float alpha)
{
    __shared__ u16 As[2][128 * 32];   // 8 KB per buffer
    __shared__ u16 Bs[2][128 * 32];

    // ---- XCD chunk swizzle (T1, bijective since total%8==0) ----
    const int gx = gridDim.x, gy = gridDim.y;
    const int total = gx * gy * gridDim.z;
    int lin = blockIdx.x + gx * (blockIdx.y + gy * blockIdx.z);
    lin = (lin & 7) * (total >> 3) + (lin >> 3);
    int bx, by, bz;
    if (gx <= gy) { bx = lin % gx; int r = lin / gx; by = r % gy; bz = r / gy; }
    else          { by = lin % gy; int r = lin / gy; bx = r % gx; bz = r / gx; }

    const int tid = threadIdx.x;
    const int wv = tid >> 6, ln = tid & 63;
    const int wr = wv >> 1, wc = wv & 1;         // wave quadrant
    const int l15 = ln & 15, l4 = ln >> 4;
    const int m0 = by * 128, n0 = bx * 128;
    const int Kc = Kdim / gridDim.z;
    const int kbeg = bz * Kc;
    const int nt = Kc / 32;

    f32x4 acc[4][4] = {};

    // Per-wave staging: wave wv, round r covers linear elements [((wv*2+r)*64+ln)*8, +8)
    const int e0 = ((wv * 2 + 0) * 64 + ln) * 8;
    const int e1 = ((wv * 2 + 1) * 64 + ln) * 8;
    const int row0 = e0 >> 5, kq0 = e0 & 31;
    const int row1 = e1 >> 5, kq1 = e1 & 31;
    const size_t arow0 = (size_t)(m0 + row0) * Kdim + kq0;
    const size_t arow1 = (size_t)(m0 + row1) * Kdim + kq1;
    const size_t brow0 = (size_t)(n0 + row0) * Kdim + kq0;
    const size_t brow1 = (size_t)(n0 + row1) * Kdim + kq1;

    // Prologue: stage tile 0
    gload16(A + arow0 + kbeg, &As[0][(wv * 2 + 0) * 512]);
    gload16(A + arow1 + kbeg, &As[0][(wv * 2 + 1) * 512]);
    gload16(B + brow0 + kbeg, &Bs[0][(wv * 2 + 0) * 512]);
    gload16(B + brow1 + kbeg, &Bs[0][(wv * 2 + 1) * 512]);
    __syncthreads();

    int cur = 0;
    for (int t = 0; t < nt; ++t) {
        // Issue next tile's staging early (hidden under this tile's MFMA)
        if (t + 1 < nt) {
            const int kk = kbeg + (t + 1) * 32;
            gload16(A + arow0 + kk, &As[cur ^ 1][(wv * 2 + 0) * 512]);
            gload16(A + arow1 + kk, &As[cur ^ 1][(wv * 2 + 1) * 512]);
            gload16(B + brow0 + kk, &Bs[cur ^ 1][(wv * 2 + 0) * 512]);
            gload16(B + brow1 + kk, &Bs[cur ^ 1][(wv * 2 + 1) * 512]);
        }
        bf16v a[4], b[4];
        #pragma unroll
        for (int i = 0; i < 4; ++i) {
            a[i] = *(const bf16v*)&As[cur][(wr * 64 + i * 16 + l15) * 32 + l4 * 8];
            b[i] = *(const bf16v*)&Bs[cur][(wc * 64 + i * 16 + l15) * 32 + l4 * 8];
        }
        #pragma unroll
        for (int i = 0; i < 4; ++i)
            #pragma unroll
            for (int j = 0; j < 4; ++j)
                acc[i][j] = __builtin_amdgcn_mfma_f32_16x16x32_bf16(a[i], b[j], acc[i][j], 0, 0, 0);
        __syncthreads();   // drains staging vmcnt; protects buf[cur] for next stage
        cur ^= 1;
    }

    // C/D layout: col = lane&15, row = (lane>>4)*4 + reg  [m89-verified]
    #pragma unroll
    for (int i = 0; i < 4; ++i)
        #pragma unroll
        for (int j = 0; j < 4; ++j)
            #pragma unroll
            for (int r = 0; r < 4; ++r) {
                const int gm = m0 + wr * 64 + i * 16 + l4 * 4 + r;
                const int gn = n0 + wc * 64 + j * 16 + l15;
                const size_t off = (size_t)gm * Ndim + gn;
                float v = alpha * acc[i][j][r];
                if (Cp) {
                    Cp[(size_t)bz * Mdim * Ndim + off] = v;
                } else {
                    if (Add) v += Add[off];
                    if (Cf) Cf[off] = v;
                    if (Cb) Cb[off] = f2bf(v);
                }
            }
}

// Sum split-K partials (+Add), write f32 and/or bf16
__global__ __launch_bounds__(256) void reduce_k(
    const float* __restrict__ Cp, int nz, int sz,
    const float* __restrict__ Add, float* __restrict__ Cf, u16* __restrict__ Cb)
{
    const size_t i = ((size_t)blockIdx.x * 256 + threadIdx.x) * 4;
    float4 s = {0.f, 0.f, 0.f, 0.f};
    for (int z = 0; z < nz; ++z) {
        float4 v = *(const float4*)(Cp + (size_t)z * sz + i);
        s.x += v.x; s.y += v.y; s.z += v.z; s.w += v.w;
    }
    if (Add) {
        float4 a = *(const float4*)(Add + i);
        s.x += a.x; s.y += a.y; s.z += a.z; s.w += a.w;
    }
    if (Cf) *(float4*)(Cf + i) = s;
    if (Cb) {
        ushort4 o; o.x = f2bf(s.x); o.y = f2bf(s.y); o.z = f2bf(s.z); o.w = f2bf(s.w);
        *(ushort4*)(Cb + i) = o;
    }
}

// fp32 -> bf16 cast (n4 = n/4 float4 groups)
__global__ __launch_bounds__(256) void cast_bf(const float* __restrict__ in,
                                               u16* __restrict__ out, int n4)
{
    const int i = blockIdx.x * 256 + threadIdx.x;
    if (i >= n4) return;
    float4 v = *(const float4*)(in + (size_t)i * 4);
    ushort4 o; o.x = f2bf(v.x); o.y = f2bf(v.y); o.z = f2bf(v.z); o.w = f2bf(v.w);
    *(ushort4*)(out + (size_t)i * 4) = o;
}

// EstuT[n][j] = Estu[j][n], fp32 -> bf16 (32x32 LDS tile)
__global__ __launch_bounds__(256) void transpose_bf(const float* __restrict__ in,
                                                    u16* __restrict__ out)
{
    __shared__ float tile[32][33];
    const int j0 = blockIdx.x * 32, n0 = blockIdx.y * 32;
    const int tx = threadIdx.x & 31, ty = threadIdx.x >> 5;
    #pragma unroll
    for (int r = 0; r < 4; ++r)
        tile[ty + r * 8][tx] = in[(size_t)(j0 + ty + r * 8) * N_ + n0 + tx];
    __syncthreads();
    #pragma unroll
    for (int r = 0; r < 4; ++r)
        out[(size_t)(n0 + ty + r * 8) * J_ + j0 + tx] = f2bf(tile[tx][ty + r * 8]);
}

// EbT[(c*5+ii)][n] = E[c][n][ii]  bf16  (B-operand for the ywE GEMM)
__global__ __launch_bounds__(256) void build_EbT(const float* __restrict__ E,
                                                 u16* __restrict__ EbT)
{
    const int c = blockIdx.x;
    for (int n = threadIdx.x; n < N_; n += 256) {
        const float* ep = E + (size_t)c * (N_ * M_) + (size_t)n * M_;
        #pragma unroll
        for (int ii = 0; ii < M_; ++ii)
            EbT[(size_t)(c * M_ + ii) * N_ + n] = f2bf(ep[ii]);
    }
}

// Pass 1: segment sums S[seg][j] = sum_{t in seg} phi[t,i]*U[t,c],  j=i*512+c
__global__ __launch_bounds__(256) void scanS(const float* __restrict__ U,
                                             const float* __restrict__ phi,
                                             float* __restrict__ S)
{
    const int j0 = (blockIdx.x * 256 + threadIdx.x) * 2;
    const int seg = blockIdx.y;
    const int i = j0 >> 9, c = j0 & 511;
    float a0 = 0.f, a1 = 0.f;
    const int t0 = seg * SEGLEN;
    for (int t = t0; t < t0 + SEGLEN; ++t) {
        float2 u = *(const float2*)(U + (size_t)t * MC_ + c);
        float ph = phi[t * KF_ + i];
        a0 += ph * u.x; a1 += ph * u.y;
    }
    *(float2*)(S + (size_t)seg * J_ + j0) = make_float2(a0, a1);
}

// Pass 2: exclusive scan over segments
__global__ __launch_bounds__(256) void scanB(const float* __restrict__ S,
                                             float* __restrict__ O)
{
    const int j0 = (blockIdx.x * 256 + threadIdx.x) * 2;
    float o0 = 0.f, o1 = 0.f;
    #pragma unroll
    for (int s = 0; s < NSEG; ++s) {
        *(float2*)(O + (size_t)s * J_ + j0) = make_float2(o0, o1);
        float2 sv = *(const float2*)(S + (size_t)s * J_ + j0);
        o0 += sv.x; o1 += sv.y;
    }
}

// Pass 3: global strict prefix, written directly as bf16 P
__global__ __launch_bounds__(256) void scanC(const float* __restrict__ U,
                                             const float* __restrict__ phi,
                                             const float* __restrict__ O,
                                             u16* __restrict__ P)
{
    const int j0 = (blockIdx.x * 256 + threadIdx.x) * 2;
    const int seg = blockIdx.y;
    const int i = j0 >> 9, c = j0 & 511;
    float2 o = *(const float2*)(O + (size_t)seg * J_ + j0);
    float a0 = o.x, a1 = o.y;
    const int t0 = seg * SEGLEN;
    for (int t = t0; t < t0 + SEGLEN; ++t) {
        ushort2 pv; pv.x = f2bf(a0); pv.y = f2bf(a1);
        *(ushort2*)(P + (size_t)t * J_ + j0) = pv;
        float2 u = *(const float2*)(U + (size_t)t * MC_ + c);
        float ph = phi[t * KF_ + i];
        a0 += ph * u.x; a1 += ph * u.y;
    }
}

// D[t,c] = bias[c] + sum_i ywE[t-4+i][c*5+i]; also writes U^0 = D
__global__ __launch_bounds__(256) void build_D(const float* __restrict__ ywE,
                                               const float* __restrict__ bias,
                                               float* __restrict__ D,
                                               float* __restrict__ U0)
{
    const int idx = blockIdx.x * 256 + threadIdx.x;
    const int t = idx >> 9, c = idx & 511;
    float v = bias[c];
    #pragma unroll
    for (int ii = 0; ii < M_; ++ii) {
        int ts = t - (M_ - 1) + ii;
        if (ts >= 0) v += ywE[(size_t)ts * (MC_ * M_) + c * M_ + ii];
    }
    D[idx] = v;
    U0[idx] = v;
}

// losses[t] = dot(X[t],Y[t]) + dot(U[t],Z[t])
__global__ __launch_bounds__(256) void rowdot(
    const float* __restrict__ X, const float* __restrict__ Y,
    const float* __restrict__ U, const float* __restrict__ Z,
    float* __restrict__ out)
{
    const int t = blockIdx.x;
    float s = 0.f;
    for (int n = threadIdx.x; n < N_; n += 256)
        s += X[(size_t)t * N_ + n] * Y[(size_t)t * N_ + n];
    for (int c = threadIdx.x; c < MC_; c += 256)
        s += U[(size_t)t * MC_ + c] * Z[(size_t)t * MC_ + c];
    __shared__ float red[256];
    red[threadIdx.x] = s;
    __syncthreads();
    for (int off = 128; off > 0; off >>= 1) {
        if (threadIdx.x < off) red[threadIdx.x] += red[threadIdx.x + off];
        __syncthreads();
    }
    if (threadIdx.x == 0) out[t] = red[0];
}

// ---------------------------------------------------------------------------
extern "C" void kernel_launch(void* const* d_in, const int* in_sizes, int n_in,
                              void* d_out, int out_size, void* d_ws, size_t ws_size,
                              hipStream_t stream)
{
    const float* Qm   = (const float*)d_in[2];
    const float* Rm   = (const float*)d_in[3];
    const float* Km   = (const float*)d_in[4];
    const float* Em   = (const float*)d_in[5];
    const float* bias = (const float*)d_in[6];
    const float* Estu = (const float*)d_in[7];   // [J_, N_]
    const float* phi  = (const float*)d_in[8];   // [T, KF]
    const float* w    = (const float*)d_in[9];   // [T, N]
    float* out = (float*)d_out;

    // ---- workspace carve-up: 99.7 MB persistent + 33.6 MB transient = 133.3 MB
    char* w8 = (char*)d_ws;
    size_t off = 0;
    auto alloc = [&](size_t bytes) -> void* {
        void* p = w8 + off; off += (bytes + 255) & ~(size_t)255; return p;
    };
    // persistent
    u16*   Pb  = (u16*)  alloc((size_t)T_ * J_ * 2);        // 41.9 MB bf16 prefix P
    u16*   Fb  = (u16*)  alloc((size_t)MC_ * J_ * 2);       // 10.5 MB bf16 F
    float* D   = (float*)alloc((size_t)T_ * MC_ * 4);
    float* U   = (float*)alloc((size_t)T_ * MC_ * 4);
    u16*   Ub  = (u16*)  alloc((size_t)T_ * MC_ * 2);
    float* S   = (float*)alloc((size_t)NSEG * J_ * 4);
    float* O   = (float*)alloc((size_t)NSEG * J_ * 4);
    float* X   = (float*)alloc((size_t)T_ * N_ * 4);
    u16*   Xb  = (u16*)  alloc((size_t)T_ * N_ * 2);
    u16*   Eb  = (u16*)  alloc((size_t)J_ * N_ * 2);        // Estu cast, then EstuT
    u16*   Qb  = (u16*)  alloc((size_t)N_ * N_ * 2);
    u16*   Rb  = (u16*)  alloc((size_t)MC_ * MC_ * 2);
    // transient region B (33.55 MB): phase 1 = {ywE, EbT, Kb, Wb}; later = split-K partials
    char*  regB = (char*)alloc((size_t)4 * T_ * N_ * 4);    // 33,554,432 B
    float* ywE = (float*)regB;                               // 21.0 MB
    u16*   EbT = (u16*)  (regB + 20971520);                  //  5.2 MB
    u16*   Kb  = (u16*)  (regB + 20971520 + 5242880);        //  1.0 MB
    u16*   Wb  = (u16*)  (regB + 20971520 + 5242880 + 1048576); // 4.2 MB
    float* Cp  = (float*)regB;                               // partials (after phase 1)
    float* Y   = (float*)Pb;                                 // aliases: Pb dead by then
    float* Z   = (float*)((char*)Pb + (size_t)T_ * N_ * 4);

    dim3 blk(256);

    // Casts to bf16
    cast_bf<<<dim3(MC_ * N_ / 1024), blk, 0, stream>>>(Km, Kb, MC_ * N_ / 4);
    cast_bf<<<dim3(N_ * N_ / 1024), blk, 0, stream>>>(Qm, Qb, N_ * N_ / 4);
    cast_bf<<<dim3(MC_ * MC_ / 1024), blk, 0, stream>>>(Rm, Rb, MC_ * MC_ / 4);
    cast_bf<<<dim3(T_ * N_ / 1024), blk, 0, stream>>>(w, Wb, T_ * N_ / 4);
    cast_bf<<<dim3(J_ * N_ / 1024), blk, 0, stream>>>(Estu, Eb, J_ * N_ / 4);
    build_EbT<<<dim3(MC_), blk, 0, stream>>>(Em, EbT);

    // F = -K @ Estu^T  -> bf16 [MC_, J_]   (grid 80x4, total 320 %8==0)
    gemm_tn<<<dim3(J_ / 128, MC_ / 128, 1), blk, 0, stream>>>(
        Kb, Eb, nullptr, nullptr, Fb, nullptr, MC_, J_, N_, -1.0f);

    // ywE[t][c*5+ii] = sum_n w[t,n]*E[c,n,ii]  (grid 20x16, total 320)
    gemm_tn<<<dim3((MC_ * M_) / 128, T_ / 128, 1), blk, 0, stream>>>(
        Wb, EbT, nullptr, ywE, nullptr, nullptr, T_, MC_ * M_, N_, 1.0f);
    build_D<<<dim3(T_ * MC_ / 256), blk, 0, stream>>>(ywE, bias, D, U);

    // EstuT overwrites Eb (safe: F-GEMM ordered before on stream)
    transpose_bf<<<dim3(J_ / 32, N_ / 32), blk, 0, stream>>>(Estu, Eb);

    // Neumann iterations: U <- D + F * prefix(U).  GEMM z=8 -> 512 blocks (2/CU)
    for (int it = 0; it < NIT; ++it) {
        scanS<<<dim3(J_ / 512, NSEG), blk, 0, stream>>>(U, phi, S);
        scanB<<<dim3(J_ / 512), blk, 0, stream>>>(S, O);
        scanC<<<dim3(J_ / 512, NSEG), blk, 0, stream>>>(U, phi, O, Pb);
        gemm_tn<<<dim3(MC_ / 128, T_ / 128, 8), blk, 0, stream>>>(
            Pb, Fb, nullptr, nullptr, nullptr, Cp, T_, MC_, J_, 1.0f);
        reduce_k<<<dim3(T_ * MC_ / 1024), blk, 0, stream>>>(
            Cp, 8, T_ * MC_, D, U, (it == NIT - 1) ? Ub : nullptr);
    }

    // Final prefix, then X = P @ Estu  (z=4 -> 512 blocks)
    scanS<<<dim3(J_ / 512, NSEG), blk, 0, stream>>>(U, phi, S);
    scanB<<<dim3(J_ / 512), blk, 0, stream>>>(S, O);
    scanC<<<dim3(J_ / 512, NSEG), blk, 0, stream>>>(U, phi, O, Pb);
    gemm_tn<<<dim3(N_ / 128, T_ / 128, 4), blk, 0, stream>>>(
        Pb, Eb, nullptr, nullptr, nullptr, Cp, T_, N_, J_, 1.0f);
    reduce_k<<<dim3(T_ * N_ / 1024), blk, 0, stream>>>(Cp, 4, T_ * N_, nullptr, X, Xb);

    // Y = X @ Q (symmetric, z=4) ; Z = U @ R (symmetric, z=4) ; losses
    gemm_tn<<<dim3(N_ / 128, T_ / 128, 4), blk, 0, stream>>>(
        Xb, Qb, nullptr, nullptr, nullptr, Cp, T_, N_, N_, 1.0f);
    reduce_k<<<dim3(T_ * N_ / 1024), blk, 0, stream>>>(Cp, 4, T_ * N_, nullptr, Y, nullptr);
    gemm_tn<<<dim3(MC_ / 128, T_ / 128, 4), blk, 0, stream>>>(
        Ub, Rb, nullptr, nullptr, nullptr, Cp, T_, MC_, MC_, 1.0f);
    reduce_k<<<dim3(T_ * MC_ / 1024), blk, 0, stream>>>(Cp, 4, T_ * MC_, nullptr, Z, nullptr);
    rowdot<<<dim3(T_), blk, 0, stream>>>(X, Y, U, Z, out);
}

// Round 5
// 509.840 us; speedup vs baseline: 21.5345x; 1.1172x over previous
//
#include <hip/hip_runtime.h>

// Problem constants (fixed by the reference)
#define T_    2048
#define N_    1024
#define MC_   512
#define KF_   20
#define M_    5
#define J_    (KF_ * MC_)      // 10240
#define NSEG  16
#define SEGLEN (T_ / NSEG)     // 128
#define NIT   3                // Neumann iterations

typedef unsigned short u16;
typedef __attribute__((ext_vector_type(8))) __bf16 bf16v;          // MFMA A/B frag
typedef __attribute__((ext_vector_type(4))) float  f32x4;          // MFMA C/D frag
typedef __attribute__((ext_vector_type(8))) unsigned short u16x8;

__device__ inline u16 f2bf(float f) {                      // RNE f32 -> bf16
    unsigned u = __float_as_uint(f);
    u += 0x7fff + ((u >> 16) & 1);
    return (u16)(u >> 16);
}
__device__ inline float bf2f(u16 v) { return __uint_as_float((unsigned)v << 16); }

__device__ inline void gload16(const void* g, void* l) {   // 16B global -> LDS (lane*16 dest)
    __builtin_amdgcn_global_load_lds((const __attribute__((address_space(1))) void*)g,
                                     (__attribute__((address_space(3))) void*)l, 16, 0, 0);
}

// ---------------------------------------------------------------------------
// bf16 MFMA GEMM, TN form: C[m,n] = alpha * sum_k A[m,k]*B[n,k]
// 128x128 tile, BK=32, 4 waves (64x64 quadrant each, 4x4 frags of 16x16x32).
// Double-buffered LDS, stage-early, one barrier per K-step.
// LDS XOR swizzle (T2, rule-#21 both-sides form): LDS dest stays linear for
// global_load_lds; the 16B chunk index within each 64B row is XORed with
// ((row>>1)&3) on the GLOBAL SOURCE address, and identically on the ds_read
// side. Bank-quad = (4*row + ch') mod 8 -> all 8 rows of an 8-lane group hit
// distinct quads -> conflict-free b128 reads.
// Cp set: grid.z splits K; bf16 partials (alpha applied) go to Cp[z].
// else: epilogue adds Add (if set), writes Cf (f32) and/or Cb (bf16).
// Block ids chunk-swizzled across 8 XCDs (bijective; total%8==0 always here).
// ---------------------------------------------------------------------------
__global__ __launch_bounds__(256) void gemm_tn(
    const u16* __restrict__ A, const u16* __restrict__ B,
    const float* __restrict__ Add, float* __restrict__ Cf,
    u16* __restrict__ Cb, u16* __restrict__ Cp,
    int Mdim, int Ndim, int Kdim, float alpha)
{
    __shared__ u16 As[2][128 * 32];   // 8 KB per buffer
    __shared__ u16 Bs[2][128 * 32];

    // ---- XCD chunk swizzle (T1, bijective since total%8==0) ----
    const int gx = gridDim.x, gy = gridDim.y;
    const int total = gx * gy * gridDim.z;
    int lin = blockIdx.x + gx * (blockIdx.y + gy * blockIdx.z);
    lin = (lin & 7) * (total >> 3) + (lin >> 3);
    int bx, by, bz;
    if (gx <= gy) { bx = lin % gx; int r = lin / gx; by = r % gy; bz = r / gy; }
    else          { by = lin % gy; int r = lin / gy; bx = r % gx; bz = r / gx; }

    const int tid = threadIdx.x;
    const int wv = tid >> 6, ln = tid & 63;
    const int wr = wv >> 1, wc = wv & 1;         // wave quadrant
    const int l15 = ln & 15, l4 = ln >> 4;
    const int m0 = by * 128, n0 = bx * 128;
    const int Kc = Kdim / gridDim.z;
    const int kbeg = bz * Kc;
    const int nt = Kc / 32;

    f32x4 acc[4][4] = {};

    // Staging addresses: chunk c = (wv*2+r)*64 + ln; row = c>>2, ch = c&3.
    // Global source chunk = ch ^ ((row>>1)&3)  (inverse == forward, XOR involution)
    const int c0 = (wv * 2 + 0) * 64 + ln;
    const int c1 = (wv * 2 + 1) * 64 + ln;
    const int row0 = c0 >> 2, kq0 = ((c0 & 3) ^ ((row0 >> 1) & 3)) * 8;
    const int row1 = c1 >> 2, kq1 = ((c1 & 3) ^ ((row1 >> 1) & 3)) * 8;
    const size_t arow0 = (size_t)(m0 + row0) * Kdim + kq0;
    const size_t arow1 = (size_t)(m0 + row1) * Kdim + kq1;
    const size_t brow0 = (size_t)(n0 + row0) * Kdim + kq0;
    const size_t brow1 = (size_t)(n0 + row1) * Kdim + kq1;

    // Fragment-read swizzle: g = ((wr*64 + i*16 + l15)>>1)&3 = (l15>>1)&3
    const int gsw = (l15 >> 1) & 3;
    const int koff = (l4 ^ gsw) * 8;

    // Prologue: stage tile 0
    gload16(A + arow0 + kbeg, &As[0][(wv * 2 + 0) * 512]);
    gload16(A + arow1 + kbeg, &As[0][(wv * 2 + 1) * 512]);
    gload16(B + brow0 + kbeg, &Bs[0][(wv * 2 + 0) * 512]);
    gload16(B + brow1 + kbeg, &Bs[0][(wv * 2 + 1) * 512]);
    __syncthreads();

    int cur = 0;
    for (int t = 0; t < nt; ++t) {
        if (t + 1 < nt) {          // stage next tile early (hidden under MFMA)
            const int kk = kbeg + (t + 1) * 32;
            gload16(A + arow0 + kk, &As[cur ^ 1][(wv * 2 + 0) * 512]);
            gload16(A + arow1 + kk, &As[cur ^ 1][(wv * 2 + 1) * 512]);
            gload16(B + brow0 + kk, &Bs[cur ^ 1][(wv * 2 + 0) * 512]);
            gload16(B + brow1 + kk, &Bs[cur ^ 1][(wv * 2 + 1) * 512]);
        }
        bf16v a[4], b[4];
        #pragma unroll
        for (int i = 0; i < 4; ++i) {
            a[i] = *(const bf16v*)&As[cur][(wr * 64 + i * 16 + l15) * 32 + koff];
            b[i] = *(const bf16v*)&Bs[cur][(wc * 64 + i * 16 + l15) * 32 + koff];
        }
        #pragma unroll
        for (int i = 0; i < 4; ++i)
            #pragma unroll
            for (int j = 0; j < 4; ++j)
                acc[i][j] = __builtin_amdgcn_mfma_f32_16x16x32_bf16(a[i], b[j], acc[i][j], 0, 0, 0);
        __syncthreads();   // drains staging vmcnt; protects buf[cur] for next stage
        cur ^= 1;
    }

    // C/D layout: col = lane&15, row = (lane>>4)*4 + reg  [m89-verified]
    #pragma unroll
    for (int i = 0; i < 4; ++i)
        #pragma unroll
        for (int j = 0; j < 4; ++j)
            #pragma unroll
            for (int r = 0; r < 4; ++r) {
                const int gm = m0 + wr * 64 + i * 16 + l4 * 4 + r;
                const int gn = n0 + wc * 64 + j * 16 + l15;
                const size_t off = (size_t)gm * Ndim + gn;
                float v = alpha * acc[i][j][r];
                if (Cp) {
                    Cp[(size_t)bz * Mdim * Ndim + off] = f2bf(v);
                } else {
                    if (Add) v += Add[off];
                    if (Cf) Cf[off] = v;
                    if (Cb) Cb[off] = f2bf(v);
                }
            }
}

// Sum bf16 split-K partials (+f32 Add), write f32 and/or bf16. 8 elems/thread.
__global__ __launch_bounds__(256) void reduce_kb(
    const u16* __restrict__ Cp, int nz, int sz,
    const float* __restrict__ Add, float* __restrict__ Cf, u16* __restrict__ Cb)
{
    const size_t i = ((size_t)blockIdx.x * 256 + threadIdx.x) * 8;
    float s[8] = {};
    for (int z = 0; z < nz; ++z) {
        u16x8 v = *(const u16x8*)(Cp + (size_t)z * sz + i);
        #pragma unroll
        for (int k = 0; k < 8; ++k) s[k] += bf2f(v[k]);
    }
    if (Add) {
        float4 a0 = *(const float4*)(Add + i);
        float4 a1 = *(const float4*)(Add + i + 4);
        s[0] += a0.x; s[1] += a0.y; s[2] += a0.z; s[3] += a0.w;
        s[4] += a1.x; s[5] += a1.y; s[6] += a1.z; s[7] += a1.w;
    }
    if (Cf) {
        *(float4*)(Cf + i)     = make_float4(s[0], s[1], s[2], s[3]);
        *(float4*)(Cf + i + 4) = make_float4(s[4], s[5], s[6], s[7]);
    }
    if (Cb) {
        u16x8 o;
        #pragma unroll
        for (int k = 0; k < 8; ++k) o[k] = f2bf(s[k]);
        *(u16x8*)(Cb + i) = o;
    }
}

// fp32 -> bf16 cast (n4 = n/4 float4 groups)
__global__ __launch_bounds__(256) void cast_bf(const float* __restrict__ in,
                                               u16* __restrict__ out, int n4)
{
    const int i = blockIdx.x * 256 + threadIdx.x;
    if (i >= n4) return;
    float4 v = *(const float4*)(in + (size_t)i * 4);
    ushort4 o; o.x = f2bf(v.x); o.y = f2bf(v.y); o.z = f2bf(v.z); o.w = f2bf(v.w);
    *(ushort4*)(out + (size_t)i * 4) = o;
}

// EstuT[n][j] = Estu[j][n], fp32 -> bf16 (32x32 LDS tile)
__global__ __launch_bounds__(256) void transpose_bf(const float* __restrict__ in,
                                                    u16* __restrict__ out)
{
    __shared__ float tile[32][33];
    const int j0 = blockIdx.x * 32, n0 = blockIdx.y * 32;
    const int tx = threadIdx.x & 31, ty = threadIdx.x >> 5;
    #pragma unroll
    for (int r = 0; r < 4; ++r)
        tile[ty + r * 8][tx] = in[(size_t)(j0 + ty + r * 8) * N_ + n0 + tx];
    __syncthreads();
    #pragma unroll
    for (int r = 0; r < 4; ++r)
        out[(size_t)(n0 + ty + r * 8) * J_ + j0 + tx] = f2bf(tile[tx][ty + r * 8]);
}

// EbT[(c*5+ii)][n] = E[c][n][ii]  bf16  (B-operand for the ywE GEMM)
__global__ __launch_bounds__(256) void build_EbT(const float* __restrict__ E,
                                                 u16* __restrict__ EbT)
{
    const int c = blockIdx.x;
    for (int n = threadIdx.x; n < N_; n += 256) {
        const float* ep = E + (size_t)c * (N_ * M_) + (size_t)n * M_;
        #pragma unroll
        for (int ii = 0; ii < M_; ++ii)
            EbT[(size_t)(c * M_ + ii) * N_ + n] = f2bf(ep[ii]);
    }
}

// Pass 1: segment sums S[seg][j] = sum_{t in seg} phi[t,i]*U[t,c],  j=i*512+c
__global__ __launch_bounds__(256) void scanS(const float* __restrict__ U,
                                             const float* __restrict__ phi,
                                             float* __restrict__ S)
{
    const int j0 = (blockIdx.x * 256 + threadIdx.x) * 2;
    const int seg = blockIdx.y;
    const int i = j0 >> 9, c = j0 & 511;
    float a0 = 0.f, a1 = 0.f;
    const int t0 = seg * SEGLEN;
    for (int t = t0; t < t0 + SEGLEN; ++t) {
        float2 u = *(const float2*)(U + (size_t)t * MC_ + c);
        float ph = phi[t * KF_ + i];
        a0 += ph * u.x; a1 += ph * u.y;
    }
    *(float2*)(S + (size_t)seg * J_ + j0) = make_float2(a0, a1);
}

// Pass 2: exclusive scan over segments
__global__ __launch_bounds__(256) void scanB(const float* __restrict__ S,
                                             float* __restrict__ O)
{
    const int j0 = (blockIdx.x * 256 + threadIdx.x) * 2;
    float o0 = 0.f, o1 = 0.f;
    #pragma unroll
    for (int s = 0; s < NSEG; ++s) {
        *(float2*)(O + (size_t)s * J_ + j0) = make_float2(o0, o1);
        float2 sv = *(const float2*)(S + (size_t)s * J_ + j0);
        o0 += sv.x; o1 += sv.y;
    }
}

// Pass 3: global strict prefix, written directly as bf16 P
__global__ __launch_bounds__(256) void scanC(const float* __restrict__ U,
                                             const float* __restrict__ phi,
                                             const float* __restrict__ O,
                                             u16* __restrict__ P)
{
    const int j0 = (blockIdx.x * 256 + threadIdx.x) * 2;
    const int seg = blockIdx.y;
    const int i = j0 >> 9, c = j0 & 511;
    float2 o = *(const float2*)(O + (size_t)seg * J_ + j0);
    float a0 = o.x, a1 = o.y;
    const int t0 = seg * SEGLEN;
    for (int t = t0; t < t0 + SEGLEN; ++t) {
        ushort2 pv; pv.x = f2bf(a0); pv.y = f2bf(a1);
        *(ushort2*)(P + (size_t)t * J_ + j0) = pv;
        float2 u = *(const float2*)(U + (size_t)t * MC_ + c);
        float ph = phi[t * KF_ + i];
        a0 += ph * u.x; a1 += ph * u.y;
    }
}

// D[t,c] = bias[c] + sum_i ywE[t-4+i][c*5+i]; also writes U^0 = D
__global__ __launch_bounds__(256) void build_D(const float* __restrict__ ywE,
                                               const float* __restrict__ bias,
                                               float* __restrict__ D,
                                               float* __restrict__ U0)
{
    const int idx = blockIdx.x * 256 + threadIdx.x;
    const int t = idx >> 9, c = idx & 511;
    float v = bias[c];
    #pragma unroll
    for (int ii = 0; ii < M_; ++ii) {
        int ts = t - (M_ - 1) + ii;
        if (ts >= 0) v += ywE[(size_t)ts * (MC_ * M_) + c * M_ + ii];
    }
    D[idx] = v;
    U0[idx] = v;
}

// losses[t] = dot(X[t],Y[t]) + dot(U[t],Z[t])
__global__ __launch_bounds__(256) void rowdot(
    const float* __restrict__ X, const float* __restrict__ Y,
    const float* __restrict__ U, const float* __restrict__ Z,
    float* __restrict__ out)
{
    const int t = blockIdx.x;
    float s = 0.f;
    for (int n = threadIdx.x; n < N_; n += 256)
        s += X[(size_t)t * N_ + n] * Y[(size_t)t * N_ + n];
    for (int c = threadIdx.x; c < MC_; c += 256)
        s += U[(size_t)t * MC_ + c] * Z[(size_t)t * MC_ + c];
    __shared__ float red[256];
    red[threadIdx.x] = s;
    __syncthreads();
    for (int off = 128; off > 0; off >>= 1) {
        if (threadIdx.x < off) red[threadIdx.x] += red[threadIdx.x + off];
        __syncthreads();
    }
    if (threadIdx.x == 0) out[t] = red[0];
}

// ---------------------------------------------------------------------------
extern "C" void kernel_launch(void* const* d_in, const int* in_sizes, int n_in,
                              void* d_out, int out_size, void* d_ws, size_t ws_size,
                              hipStream_t stream)
{
    const float* Qm   = (const float*)d_in[2];
    const float* Rm   = (const float*)d_in[3];
    const float* Km   = (const float*)d_in[4];
    const float* Em   = (const float*)d_in[5];
    const float* bias = (const float*)d_in[6];
    const float* Estu = (const float*)d_in[7];   // [J_, N_]
    const float* phi  = (const float*)d_in[8];   // [T, KF]
    const float* w    = (const float*)d_in[9];   // [T, N]
    float* out = (float*)d_out;

    // ---- workspace carve-up: ~134.0 MB total (<= 134.87 proven in round 1)
    char* w8 = (char*)d_ws;
    size_t off = 0;
    auto alloc = [&](size_t bytes) -> void* {
        void* p = w8 + off; off += (bytes + 255) & ~(size_t)255; return p;
    };
    // persistent
    u16*   Pb  = (u16*)  alloc((size_t)T_ * J_ * 2);        // 41.9 MB bf16 prefix P
    u16*   Fb  = (u16*)  alloc((size_t)MC_ * J_ * 2);       // 10.5 MB bf16 F
    float* D   = (float*)alloc((size_t)T_ * MC_ * 4);
    float* U   = (float*)alloc((size_t)T_ * MC_ * 4);
    u16*   Ub  = (u16*)  alloc((size_t)T_ * MC_ * 2);
    float* S   = (float*)alloc((size_t)NSEG * J_ * 4);
    float* O   = (float*)alloc((size_t)NSEG * J_ * 4);
    float* X   = (float*)alloc((size_t)T_ * N_ * 4);
    u16*   Xb  = (u16*)  alloc((size_t)T_ * N_ * 2);
    u16*   Eb  = (u16*)  alloc((size_t)J_ * N_ * 2);        // Estu cast, then EstuT
    u16*   Qb  = (u16*)  alloc((size_t)N_ * N_ * 2);
    u16*   Rb  = (u16*)  alloc((size_t)MC_ * MC_ * 2);
    // transient region B (33.55 MB): phase 1 = {ywE, EbT, Kb, Wb}; later = bf16 split-K partials
    char*  regB = (char*)alloc((size_t)4 * T_ * N_ * 4);    // 33,554,432 B
    float* ywE = (float*)regB;                               // 21.0 MB
    u16*   EbT = (u16*)  (regB + 20971520);                  //  5.2 MB
    u16*   Kb  = (u16*)  (regB + 20971520 + 5242880);        //  1.0 MB
    u16*   Wb  = (u16*)  (regB + 20971520 + 5242880 + 1048576); // 4.2 MB
    u16*   Cp  = (u16*)regB;                                 // bf16 partials (after phase 1)
    u16*   CpP = (u16*)Pb;                                   // partials for F/ywE (Pb free then)
    float* Y   = (float*)Pb;                                 // aliases: Pb dead by then
    float* Z   = (float*)((char*)Pb + (size_t)T_ * N_ * 4);

    dim3 blk(256);

    // Casts to bf16
    cast_bf<<<dim3(MC_ * N_ / 1024), blk, 0, stream>>>(Km, Kb, MC_ * N_ / 4);
    cast_bf<<<dim3(N_ * N_ / 1024), blk, 0, stream>>>(Qm, Qb, N_ * N_ / 4);
    cast_bf<<<dim3(MC_ * MC_ / 1024), blk, 0, stream>>>(Rm, Rb, MC_ * MC_ / 4);
    cast_bf<<<dim3(T_ * N_ / 1024), blk, 0, stream>>>(w, Wb, T_ * N_ / 4);
    cast_bf<<<dim3(J_ * N_ / 1024), blk, 0, stream>>>(Estu, Eb, J_ * N_ / 4);
    build_EbT<<<dim3(MC_), blk, 0, stream>>>(Em, EbT);

    // F = -K @ Estu^T -> bf16 [MC_, J_]   (z=2, partials in Pb region; 640 blocks)
    gemm_tn<<<dim3(J_ / 128, MC_ / 128, 2), blk, 0, stream>>>(
        Kb, Eb, nullptr, nullptr, nullptr, CpP, MC_, J_, N_, -1.0f);
    reduce_kb<<<dim3(MC_ * J_ / 2048), blk, 0, stream>>>(
        CpP, 2, MC_ * J_, nullptr, nullptr, Fb);

    // ywE[t][c*5+ii] = sum_n w[t,n]*E[c,n,ii]  (z=2, partials in Pb; 640 blocks)
    gemm_tn<<<dim3((MC_ * M_) / 128, T_ / 128, 2), blk, 0, stream>>>(
        Wb, EbT, nullptr, nullptr, nullptr, CpP, T_, MC_ * M_, N_, 1.0f);
    reduce_kb<<<dim3(T_ * (MC_ * M_) / 2048), blk, 0, stream>>>(
        CpP, 2, T_ * (MC_ * M_), nullptr, ywE, nullptr);
    build_D<<<dim3(T_ * MC_ / 256), blk, 0, stream>>>(ywE, bias, D, U);

    // EstuT overwrites Eb (safe: F-GEMM ordered before on stream)
    transpose_bf<<<dim3(J_ / 32, N_ / 32), blk, 0, stream>>>(Estu, Eb);

    // Neumann iterations: U <- D + F * prefix(U).  z=16 -> 1024 blocks (4/CU)
    for (int it = 0; it < NIT; ++it) {
        scanS<<<dim3(J_ / 512, NSEG), blk, 0, stream>>>(U, phi, S);
        scanB<<<dim3(J_ / 512), blk, 0, stream>>>(S, O);
        scanC<<<dim3(J_ / 512, NSEG), blk, 0, stream>>>(U, phi, O, Pb);
        gemm_tn<<<dim3(MC_ / 128, T_ / 128, 16), blk, 0, stream>>>(
            Pb, Fb, nullptr, nullptr, nullptr, Cp, T_, MC_, J_, 1.0f);
        reduce_kb<<<dim3(T_ * MC_ / 2048), blk, 0, stream>>>(
            Cp, 16, T_ * MC_, D, U, (it == NIT - 1) ? Ub : nullptr);
    }

    // Final prefix, then X = P @ Estu  (z=8 -> 1024 blocks)
    scanS<<<dim3(J_ / 512, NSEG), blk, 0, stream>>>(U, phi, S);
    scanB<<<dim3(J_ / 512), blk, 0, stream>>>(S, O);
    scanC<<<dim3(J_ / 512, NSEG), blk, 0, stream>>>(U, phi, O, Pb);
    gemm_tn<<<dim3(N_ / 128, T_ / 128, 8), blk, 0, stream>>>(
        Pb, Eb, nullptr, nullptr, nullptr, Cp, T_, N_, J_, 1.0f);
    reduce_kb<<<dim3(T_ * N_ / 2048), blk, 0, stream>>>(
        Cp, 8, T_ * N_, nullptr, X, Xb);

    // Y = X @ Q (symmetric, z=8) ; Z = U @ R (symmetric, z=8) ; losses
    gemm_tn<<<dim3(N_ / 128, T_ / 128, 8), blk, 0, stream>>>(
        Xb, Qb, nullptr, nullptr, nullptr, Cp, T_, N_, N_, 1.0f);
    reduce_kb<<<dim3(T_ * N_ / 2048), blk, 0, stream>>>(
        Cp, 8, T_ * N_, nullptr, Y, nullptr);
    gemm_tn<<<dim3(MC_ / 128, T_ / 128, 8), blk, 0, stream>>>(
        Ub, Rb, nullptr, nullptr, nullptr, Cp, T_, MC_, MC_, 1.0f);
    reduce_kb<<<dim3(T_ * MC_ / 2048), blk, 0, stream>>>(
        Cp, 8, T_ * MC_, nullptr, Z, nullptr);
    rowdot<<<dim3(T_), blk, 0, stream>>>(X, Y, U, Z, out);
}

// Round 6
// 393.229 us; speedup vs baseline: 27.9205x; 1.2965x over previous
//
#include <hip/hip_runtime.h>

// Problem constants (fixed by the reference)
#define T_    2048
#define N_    1024
#define MC_   512
#define KF_   20
#define M_    5
#define J_    (KF_ * MC_)      // 10240
#define NSEG  16
#define SEGLEN (T_ / NSEG)     // 128
#define NIT   2                // Neumann iterations (err ~ ||L||^3 ~ 2e-5 << bf16 noise)

typedef unsigned short u16;
typedef __attribute__((ext_vector_type(8))) __bf16 bf16v;          // MFMA A/B frag
typedef __attribute__((ext_vector_type(4))) float  f32x4;          // MFMA C/D frag
typedef __attribute__((ext_vector_type(8))) unsigned short u16x8;

__device__ inline u16 f2bf(float f) {                      // RNE f32 -> bf16
    unsigned u = __float_as_uint(f);
    u += 0x7fff + ((u >> 16) & 1);
    return (u16)(u >> 16);
}
__device__ inline float bf2f(u16 v) { return __uint_as_float((unsigned)v << 16); }

__device__ inline void gload16(const void* g, void* l) {   // 16B global -> LDS (lane*16 dest)
    __builtin_amdgcn_global_load_lds((const __attribute__((address_space(1))) void*)g,
                                     (__attribute__((address_space(3))) void*)l, 16, 0, 0);
}

// ---------------------------------------------------------------------------
// bf16 MFMA GEMM, TN form: C[m,n] = alpha * sum_k A[m,k]*B[n,k]
// 128x128 tile, BK=64, 4 waves (64x64 quadrant each; 4x4 frags x 2 K-subs).
// Double-buffered LDS (64 KB total), stage-early, one barrier per K-step.
// 32 MFMA per wave per K-step (~156cy) vs one staged-load latency (~300-400cy):
// duty ~39% x 2 blocks/CU -> target MfmaUtil ~40%.
// LDS swizzle (BK=64: row = 128B = exactly one bank cycle, worst case):
// 16B chunk index ch (0..7) within each row is XORed with (row&7) on the
// GLOBAL SOURCE of global_load_lds (LDS dest linear) and identically on the
// ds_read side. Each aligned 8-lane read group spans rows r..r+7 at fixed ch
// -> quads ch^(0..7) all distinct -> conflict-free (criterion validated r5).
// Cp set: grid.z splits K (Kdim/gridDim.z % 64 == 0); bf16 partials to Cp[z].
// else: epilogue adds Add (if set), writes Cf (f32) and/or Cb (bf16).
// Block ids chunk-swizzled across 8 XCDs (bijective; total%8==0 always here).
// ---------------------------------------------------------------------------
__global__ __launch_bounds__(256) void gemm_tn(
    const u16* __restrict__ A, const u16* __restrict__ B,
    const float* __restrict__ Add, float* __restrict__ Cf,
    u16* __restrict__ Cb, u16* __restrict__ Cp,
    int Mdim, int Ndim, int Kdim, float alpha)
{
    __shared__ u16 As[2][128 * 64];   // 16 KB per buffer
    __shared__ u16 Bs[2][128 * 64];

    // ---- XCD chunk swizzle (T1, bijective since total%8==0) ----
    const int gx = gridDim.x, gy = gridDim.y;
    const int total = gx * gy * gridDim.z;
    int lin = blockIdx.x + gx * (blockIdx.y + gy * blockIdx.z);
    lin = (lin & 7) * (total >> 3) + (lin >> 3);
    int bx, by, bz;
    if (gx <= gy) { bx = lin % gx; int r = lin / gx; by = r % gy; bz = r / gy; }
    else          { by = lin % gy; int r = lin / gy; bx = r % gx; bz = r / gx; }

    const int tid = threadIdx.x;
    const int wv = tid >> 6, ln = tid & 63;
    const int wr = wv >> 1, wc = wv & 1;         // wave quadrant
    const int l15 = ln & 15, l4 = ln >> 4;
    const int m0 = by * 128, n0 = bx * 128;
    const int Kc = Kdim / gridDim.z;
    const int kbeg = bz * Kc;
    const int nt = Kc / 64;

    f32x4 acc[4][4] = {};

    // Staging: 128x64 tile = 1024 chunks of 16B; thread handles 4 chunks per
    // matrix: c_q = q*256 + tid. row = c>>3, ch = c&7; global source chunk is
    // ch ^ (row&7); LDS dest linear (wave-uniform base + lane*16).
    size_t arow[4], brow[4];
    int lbase[4];
    #pragma unroll
    for (int q = 0; q < 4; ++q) {
        const int c = q * 256 + tid;
        const int row = c >> 3, ch = c & 7;
        const int src = ((ch ^ (row & 7)) * 8);
        arow[q] = (size_t)(m0 + row) * Kdim + src;
        brow[q] = (size_t)(n0 + row) * Kdim + src;
        lbase[q] = (q * 256 + wv * 64) * 8;      // elements; wave-uniform
    }

    // Fragment-read swizzle: row&7 == l15&7 for every frag row.
    const int fsw = l15 & 7;

    // Prologue: stage tile 0
    #pragma unroll
    for (int q = 0; q < 4; ++q) {
        gload16(A + arow[q] + kbeg, &As[0][lbase[q]]);
        gload16(B + brow[q] + kbeg, &Bs[0][lbase[q]]);
    }
    __syncthreads();

    int cur = 0;
    for (int t = 0; t < nt; ++t) {
        if (t + 1 < nt) {          // stage next tile early (hidden under MFMA)
            const int kk = kbeg + (t + 1) * 64;
            #pragma unroll
            for (int q = 0; q < 4; ++q) {
                gload16(A + arow[q] + kk, &As[cur ^ 1][lbase[q]]);
                gload16(B + brow[q] + kk, &Bs[cur ^ 1][lbase[q]]);
            }
        }
        bf16v a[4][2], b[4][2];
        #pragma unroll
        for (int i = 0; i < 4; ++i)
            #pragma unroll
            for (int s = 0; s < 2; ++s) {
                const int ch = ((s * 4 + l4) ^ fsw) * 8;
                a[i][s] = *(const bf16v*)&As[cur][(wr * 64 + i * 16 + l15) * 64 + ch];
                b[i][s] = *(const bf16v*)&Bs[cur][(wc * 64 + i * 16 + l15) * 64 + ch];
            }
        #pragma unroll
        for (int s = 0; s < 2; ++s)
            #pragma unroll
            for (int i = 0; i < 4; ++i)
                #pragma unroll
                for (int j = 0; j < 4; ++j)
                    acc[i][j] = __builtin_amdgcn_mfma_f32_16x16x32_bf16(
                        a[i][s], b[j][s], acc[i][j], 0, 0, 0);
        __syncthreads();   // drains staging vmcnt; protects buf[cur] for next stage
        cur ^= 1;
    }

    // C/D layout: col = lane&15, row = (lane>>4)*4 + reg  [m89-verified]
    #pragma unroll
    for (int i = 0; i < 4; ++i)
        #pragma unroll
        for (int j = 0; j < 4; ++j)
            #pragma unroll
            for (int r = 0; r < 4; ++r) {
                const int gm = m0 + wr * 64 + i * 16 + l4 * 4 + r;
                const int gn = n0 + wc * 64 + j * 16 + l15;
                const size_t off = (size_t)gm * Ndim + gn;
                float v = alpha * acc[i][j][r];
                if (Cp) {
                    Cp[(size_t)bz * Mdim * Ndim + off] = f2bf(v);
                } else {
                    if (Add) v += Add[off];
                    if (Cf) Cf[off] = v;
                    if (Cb) Cb[off] = f2bf(v);
                }
            }
}

// Sum bf16 split-K partials (+f32 Add), write f32 and/or bf16. 8 elems/thread.
__global__ __launch_bounds__(256) void reduce_kb(
    const u16* __restrict__ Cp, int nz, int sz,
    const float* __restrict__ Add, float* __restrict__ Cf, u16* __restrict__ Cb)
{
    const size_t i = ((size_t)blockIdx.x * 256 + threadIdx.x) * 8;
    float s[8] = {};
    for (int z = 0; z < nz; ++z) {
        u16x8 v = *(const u16x8*)(Cp + (size_t)z * sz + i);
        #pragma unroll
        for (int k = 0; k < 8; ++k) s[k] += bf2f(v[k]);
    }
    if (Add) {
        float4 a0 = *(const float4*)(Add + i);
        float4 a1 = *(const float4*)(Add + i + 4);
        s[0] += a0.x; s[1] += a0.y; s[2] += a0.z; s[3] += a0.w;
        s[4] += a1.x; s[5] += a1.y; s[6] += a1.z; s[7] += a1.w;
    }
    if (Cf) {
        *(float4*)(Cf + i)     = make_float4(s[0], s[1], s[2], s[3]);
        *(float4*)(Cf + i + 4) = make_float4(s[4], s[5], s[6], s[7]);
    }
    if (Cb) {
        u16x8 o;
        #pragma unroll
        for (int k = 0; k < 8; ++k) o[k] = f2bf(s[k]);
        *(u16x8*)(Cb + i) = o;
    }
}

// fp32 -> bf16 cast (n4 = n/4 float4 groups)
__global__ __launch_bounds__(256) void cast_bf(const float* __restrict__ in,
                                               u16* __restrict__ out, int n4)
{
    const int i = blockIdx.x * 256 + threadIdx.x;
    if (i >= n4) return;
    float4 v = *(const float4*)(in + (size_t)i * 4);
    ushort4 o; o.x = f2bf(v.x); o.y = f2bf(v.y); o.z = f2bf(v.z); o.w = f2bf(v.w);
    *(ushort4*)(out + (size_t)i * 4) = o;
}

// EstuT[n][j] = Estu[j][n], fp32 -> bf16 (32x32 LDS tile)
__global__ __launch_bounds__(256) void transpose_bf(const float* __restrict__ in,
                                                    u16* __restrict__ out)
{
    __shared__ float tile[32][33];
    const int j0 = blockIdx.x * 32, n0 = blockIdx.y * 32;
    const int tx = threadIdx.x & 31, ty = threadIdx.x >> 5;
    #pragma unroll
    for (int r = 0; r < 4; ++r)
        tile[ty + r * 8][tx] = in[(size_t)(j0 + ty + r * 8) * N_ + n0 + tx];
    __syncthreads();
    #pragma unroll
    for (int r = 0; r < 4; ++r)
        out[(size_t)(n0 + ty + r * 8) * J_ + j0 + tx] = f2bf(tile[tx][ty + r * 8]);
}

// EbT[(c*5+ii)][n] = E[c][n][ii]  bf16  (B-operand for the ywE GEMM)
__global__ __launch_bounds__(256) void build_EbT(const float* __restrict__ E,
                                                 u16* __restrict__ EbT)
{
    const int c = blockIdx.x;
    for (int n = threadIdx.x; n < N_; n += 256) {
        const float* ep = E + (size_t)c * (N_ * M_) + (size_t)n * M_;
        #pragma unroll
        for (int ii = 0; ii < M_; ++ii)
            EbT[(size_t)(c * M_ + ii) * N_ + n] = f2bf(ep[ii]);
    }
}

// Pass 1: segment sums S[seg][j] = sum_{t in seg} phi[t,i]*U[t,c],  j=i*512+c
__global__ __launch_bounds__(256) void scanS(const float* __restrict__ U,
                                             const float* __restrict__ phi,
                                             float* __restrict__ S)
{
    const int j0 = (blockIdx.x * 256 + threadIdx.x) * 2;
    const int seg = blockIdx.y;
    const int i = j0 >> 9, c = j0 & 511;
    float a0 = 0.f, a1 = 0.f;
    const int t0 = seg * SEGLEN;
    for (int t = t0; t < t0 + SEGLEN; ++t) {
        float2 u = *(const float2*)(U + (size_t)t * MC_ + c);
        float ph = phi[t * KF_ + i];
        a0 += ph * u.x; a1 += ph * u.y;
    }
    *(float2*)(S + (size_t)seg * J_ + j0) = make_float2(a0, a1);
}

// Pass 2: exclusive scan over segments
__global__ __launch_bounds__(256) void scanB(const float* __restrict__ S,
                                             float* __restrict__ O)
{
    const int j0 = (blockIdx.x * 256 + threadIdx.x) * 2;
    float o0 = 0.f, o1 = 0.f;
    #pragma unroll
    for (int s = 0; s < NSEG; ++s) {
        *(float2*)(O + (size_t)s * J_ + j0) = make_float2(o0, o1);
        float2 sv = *(const float2*)(S + (size_t)s * J_ + j0);
        o0 += sv.x; o1 += sv.y;
    }
}

// Pass 3: global strict prefix, written directly as bf16 P
__global__ __launch_bounds__(256) void scanC(const float* __restrict__ U,
                                             const float* __restrict__ phi,
                                             const float* __restrict__ O,
                                             u16* __restrict__ P)
{
    const int j0 = (blockIdx.x * 256 + threadIdx.x) * 2;
    const int seg = blockIdx.y;
    const int i = j0 >> 9, c = j0 & 511;
    float2 o = *(const float2*)(O + (size_t)seg * J_ + j0);
    float a0 = o.x, a1 = o.y;
    const int t0 = seg * SEGLEN;
    for (int t = t0; t < t0 + SEGLEN; ++t) {
        ushort2 pv; pv.x = f2bf(a0); pv.y = f2bf(a1);
        *(ushort2*)(P + (size_t)t * J_ + j0) = pv;
        float2 u = *(const float2*)(U + (size_t)t * MC_ + c);
        float ph = phi[t * KF_ + i];
        a0 += ph * u.x; a1 += ph * u.y;
    }
}

// D[t,c] = bias[c] + sum_i ywE[t-4+i][c*5+i]; also writes U^0 = D
__global__ __launch_bounds__(256) void build_D(const float* __restrict__ ywE,
                                               const float* __restrict__ bias,
                                               float* __restrict__ D,
                                               float* __restrict__ U0)
{
    const int idx = blockIdx.x * 256 + threadIdx.x;
    const int t = idx >> 9, c = idx & 511;
    float v = bias[c];
    #pragma unroll
    for (int ii = 0; ii < M_; ++ii) {
        int ts = t - (M_ - 1) + ii;
        if (ts >= 0) v += ywE[(size_t)ts * (MC_ * M_) + c * M_ + ii];
    }
    D[idx] = v;
    U0[idx] = v;
}

// losses[t] = dot(X[t],Y[t]) + dot(U[t],Z[t])
__global__ __launch_bounds__(256) void rowdot(
    const float* __restrict__ X, const float* __restrict__ Y,
    const float* __restrict__ U, const float* __restrict__ Z,
    float* __restrict__ out)
{
    const int t = blockIdx.x;
    float s = 0.f;
    for (int n = threadIdx.x; n < N_; n += 256)
        s += X[(size_t)t * N_ + n] * Y[(size_t)t * N_ + n];
    for (int c = threadIdx.x; c < MC_; c += 256)
        s += U[(size_t)t * MC_ + c] * Z[(size_t)t * MC_ + c];
    __shared__ float red[256];
    red[threadIdx.x] = s;
    __syncthreads();
    for (int off = 128; off > 0; off >>= 1) {
        if (threadIdx.x < off) red[threadIdx.x] += red[threadIdx.x + off];
        __syncthreads();
    }
    if (threadIdx.x == 0) out[t] = red[0];
}

// ---------------------------------------------------------------------------
extern "C" void kernel_launch(void* const* d_in, const int* in_sizes, int n_in,
                              void* d_out, int out_size, void* d_ws, size_t ws_size,
                              hipStream_t stream)
{
    const float* Qm   = (const float*)d_in[2];
    const float* Rm   = (const float*)d_in[3];
    const float* Km   = (const float*)d_in[4];
    const float* Em   = (const float*)d_in[5];
    const float* bias = (const float*)d_in[6];
    const float* Estu = (const float*)d_in[7];   // [J_, N_]
    const float* phi  = (const float*)d_in[8];   // [T, KF]
    const float* w    = (const float*)d_in[9];   // [T, N]
    float* out = (float*)d_out;

    // ---- workspace carve-up: ~134.0 MB total (<= 134.87 proven in round 1)
    char* w8 = (char*)d_ws;
    size_t off = 0;
    auto alloc = [&](size_t bytes) -> void* {
        void* p = w8 + off; off += (bytes + 255) & ~(size_t)255; return p;
    };
    // persistent
    u16*   Pb  = (u16*)  alloc((size_t)T_ * J_ * 2);        // 41.9 MB bf16 prefix P
    u16*   Fb  = (u16*)  alloc((size_t)MC_ * J_ * 2);       // 10.5 MB bf16 F
    float* D   = (float*)alloc((size_t)T_ * MC_ * 4);
    float* U   = (float*)alloc((size_t)T_ * MC_ * 4);
    u16*   Ub  = (u16*)  alloc((size_t)T_ * MC_ * 2);
    float* S   = (float*)alloc((size_t)NSEG * J_ * 4);
    float* O   = (float*)alloc((size_t)NSEG * J_ * 4);
    float* X   = (float*)alloc((size_t)T_ * N_ * 4);
    u16*   Xb  = (u16*)  alloc((size_t)T_ * N_ * 2);
    u16*   Eb  = (u16*)  alloc((size_t)J_ * N_ * 2);        // Estu cast, then EstuT
    u16*   Qb  = (u16*)  alloc((size_t)N_ * N_ * 2);
    u16*   Rb  = (u16*)  alloc((size_t)MC_ * MC_ * 2);
    // transient region B (33.55 MB): phase 1 = {ywE, EbT, Kb, Wb}; later = bf16 split-K partials
    char*  regB = (char*)alloc((size_t)4 * T_ * N_ * 4);    // 33,554,432 B
    float* ywE = (float*)regB;                               // 21.0 MB
    u16*   EbT = (u16*)  (regB + 20971520);                  //  5.2 MB
    u16*   Kb  = (u16*)  (regB + 20971520 + 5242880);        //  1.0 MB
    u16*   Wb  = (u16*)  (regB + 20971520 + 5242880 + 1048576); // 4.2 MB
    u16*   Cp  = (u16*)regB;                                 // bf16 partials (after phase 1)
    u16*   CpP = (u16*)Pb;                                   // partials for F/ywE (Pb free then)
    float* Y   = (float*)Pb;                                 // aliases: Pb dead by then
    float* Z   = (float*)((char*)Pb + (size_t)T_ * N_ * 4);

    dim3 blk(256);

    // Casts to bf16
    cast_bf<<<dim3(MC_ * N_ / 1024), blk, 0, stream>>>(Km, Kb, MC_ * N_ / 4);
    cast_bf<<<dim3(N_ * N_ / 1024), blk, 0, stream>>>(Qm, Qb, N_ * N_ / 4);
    cast_bf<<<dim3(MC_ * MC_ / 1024), blk, 0, stream>>>(Rm, Rb, MC_ * MC_ / 4);
    cast_bf<<<dim3(T_ * N_ / 1024), blk, 0, stream>>>(w, Wb, T_ * N_ / 4);
    cast_bf<<<dim3(J_ * N_ / 1024), blk, 0, stream>>>(Estu, Eb, J_ * N_ / 4);
    build_EbT<<<dim3(MC_), blk, 0, stream>>>(Em, EbT);

    // F = -K @ Estu^T -> bf16 [MC_, J_]   (z=2, Kc=512=8 steps; 640 blocks)
    gemm_tn<<<dim3(J_ / 128, MC_ / 128, 2), blk, 0, stream>>>(
        Kb, Eb, nullptr, nullptr, nullptr, CpP, MC_, J_, N_, -1.0f);
    reduce_kb<<<dim3(MC_ * J_ / 2048), blk, 0, stream>>>(
        CpP, 2, MC_ * J_, nullptr, nullptr, Fb);

    // ywE[t][c*5+ii] = sum_n w[t,n]*E[c,n,ii]  (z=2; 640 blocks)
    gemm_tn<<<dim3((MC_ * M_) / 128, T_ / 128, 2), blk, 0, stream>>>(
        Wb, EbT, nullptr, nullptr, nullptr, CpP, T_, MC_ * M_, N_, 1.0f);
    reduce_kb<<<dim3(T_ * (MC_ * M_) / 2048), blk, 0, stream>>>(
        CpP, 2, T_ * (MC_ * M_), nullptr, ywE, nullptr);
    build_D<<<dim3(T_ * MC_ / 256), blk, 0, stream>>>(ywE, bias, D, U);

    // EstuT overwrites Eb (safe: F-GEMM ordered before on stream)
    transpose_bf<<<dim3(J_ / 32, N_ / 32), blk, 0, stream>>>(Estu, Eb);

    // Neumann iterations: U <- D + F * prefix(U).  z=16 -> Kc=640=10 steps; 1024 blocks
    for (int it = 0; it < NIT; ++it) {
        scanS<<<dim3(J_ / 512, NSEG), blk, 0, stream>>>(U, phi, S);
        scanB<<<dim3(J_ / 512), blk, 0, stream>>>(S, O);
        scanC<<<dim3(J_ / 512, NSEG), blk, 0, stream>>>(U, phi, O, Pb);
        gemm_tn<<<dim3(MC_ / 128, T_ / 128, 16), blk, 0, stream>>>(
            Pb, Fb, nullptr, nullptr, nullptr, Cp, T_, MC_, J_, 1.0f);
        reduce_kb<<<dim3(T_ * MC_ / 2048), blk, 0, stream>>>(
            Cp, 16, T_ * MC_, D, U, (it == NIT - 1) ? Ub : nullptr);
    }

    // Final prefix, then X = P @ Estu  (z=8 -> Kc=1280=20 steps; 1024 blocks)
    scanS<<<dim3(J_ / 512, NSEG), blk, 0, stream>>>(U, phi, S);
    scanB<<<dim3(J_ / 512), blk, 0, stream>>>(S, O);
    scanC<<<dim3(J_ / 512, NSEG), blk, 0, stream>>>(U, phi, O, Pb);
    gemm_tn<<<dim3(N_ / 128, T_ / 128, 8), blk, 0, stream>>>(
        Pb, Eb, nullptr, nullptr, nullptr, Cp, T_, N_, J_, 1.0f);
    reduce_kb<<<dim3(T_ * N_ / 2048), blk, 0, stream>>>(
        Cp, 8, T_ * N_, nullptr, X, Xb);

    // Y = X @ Q (symmetric, z=4, Kc=256=4 steps, 512 blocks)
    gemm_tn<<<dim3(N_ / 128, T_ / 128, 4), blk, 0, stream>>>(
        Xb, Qb, nullptr, nullptr, nullptr, Cp, T_, N_, N_, 1.0f);
    reduce_kb<<<dim3(T_ * N_ / 2048), blk, 0, stream>>>(
        Cp, 4, T_ * N_, nullptr, Y, nullptr);
    // Z = U @ R (symmetric, z=4, Kc=128=2 steps, 256 blocks)
    gemm_tn<<<dim3(MC_ / 128, T_ / 128, 4), blk, 0, stream>>>(
        Ub, Rb, nullptr, nullptr, nullptr, Cp, T_, MC_, MC_, 1.0f);
    reduce_kb<<<dim3(T_ * MC_ / 2048), blk, 0, stream>>>(
        Cp, 4, T_ * MC_, nullptr, Z, nullptr);
    rowdot<<<dim3(T_), blk, 0, stream>>>(X, Y, U, Z, out);
}